// Round 10
// baseline (9360.844 us; speedup 1.0000x reference)
//
#include <hip/hip_runtime.h>

// Seq2seq LSTM + attention — persistent kernels, ROUND-20: data-as-flag enc.
//
// Ledger: R12 dataflow 5735. R15/16 dec merge 5574. R19 flag replication
// 5239 (WIN, but from the DECODER's 1024-poller contention; enc null at
// 3210us/6.27us-step). R13/R14/R17 regressions documented in git log.
//
// R20 theory: enc chain still pays producer vmcnt-drain -> flag store ->
// consumer flag-poll RTT -> SEPARATE h-load RTT. The flag is removable:
// h in (-1,1) and each producer emits its per-lane pair as ONE 8B atomic
// store (single-copy atomic) -> data can carry validity. Pre-fill encH
// slots 1..512 with sentinel 0x7F7F7F7F (3.4e38, unreachable: |h|<1;
// slot0 h0~N(0,1) can't hit it either). Consumer polls the exact words it
// consumes with agent-scope 8B atomic loads, 4-quad groups (VGPR-lean):
// value != sentinel => value IS the data. Removes drain + flag store +
// one full RTT. Decoder keeps R19 replicated flags (its win).
// Predict: enc 3210 -> ~2500-2800, total -> ~4500-4850, VGPR ~90-110,
// absmax 0.0. Null => encoder at topology floor; pivot to decoder.

namespace {

#define H_SENTINEL 0x7F7F7F7Fu

__device__ __forceinline__ float fsigmoid(float x) {
    return 1.0f / (1.0f + __expf(-x));
}
__device__ __forceinline__ float ftanh(float x) {
    float e = __expf(2.0f * x);
    return 1.0f - 2.0f / (e + 1.0f);
}

__device__ __forceinline__ void coh_store(float* p, float v) {
    __hip_atomic_store(p, v, __ATOMIC_RELAXED, __HIP_MEMORY_SCOPE_AGENT);
}
__device__ __forceinline__ void coh_store2(float* p, float2 v) {
    union { float2 f; unsigned long long u; } cv; cv.f = v;
    __hip_atomic_store((unsigned long long*)p, cv.u,
                       __ATOMIC_RELAXED, __HIP_MEMORY_SCOPE_AGENT);
}

// ---- replicated dataflow flags (decoder only) ----------------------------
__device__ __forceinline__ void post_flag_rep(unsigned* flags, int stride,
                                              int idx, unsigned val) {
    if (threadIdx.x == 0) {
        asm volatile("s_waitcnt vmcnt(0)" ::: "memory");
        #pragma unroll
        for (int r = 0; r < 8; ++r)
            __hip_atomic_store(&flags[r * stride + idx], val,
                               __ATOMIC_RELAXED, __HIP_MEMORY_SCOPE_AGENT);
    }
}
__device__ __forceinline__ void wait_group(const unsigned* flags, int base,
                                           int mask, unsigned val) {
    const unsigned* f = flags + base + (threadIdx.x & mask);
    for (;;) {
        unsigned x = __hip_atomic_load(f, __ATOMIC_RELAXED, __HIP_MEMORY_SCOPE_AGENT);
        if (__all(x >= val)) break;
        __builtin_amdgcn_s_sleep(1);
    }
    asm volatile("" ::: "memory");   // no hoisting of data loads above poll
}
__device__ __forceinline__ void wait_lstm_inputs(const unsigned* attnF,
                                                 const unsigned* lstmF,
                                                 int w, unsigned val) {
    int lane = threadIdx.x & 63;
    const unsigned* fa = attnF + lane * 2;
    const unsigned* fl = lstmF + (w & 3) * 32 + (lane & 31);
    for (;;) {
        unsigned a = __hip_atomic_load(fa + 0, __ATOMIC_RELAXED, __HIP_MEMORY_SCOPE_AGENT);
        unsigned b = __hip_atomic_load(fa + 1, __ATOMIC_RELAXED, __HIP_MEMORY_SCOPE_AGENT);
        unsigned c = __hip_atomic_load(fl,     __ATOMIC_RELAXED, __HIP_MEMORY_SCOPE_AGENT);
        int ok = (a >= val) && (b >= val) && (c >= val);
        if (__all(ok)) break;
        __builtin_amdgcn_s_sleep(1);
    }
    asm volatile("" ::: "memory");
}

// ---- transpose input_seq (B,S,F) -> quad layout [s][f/4][b][4] -----------
__global__ __launch_bounds__(256) void k_transpose_input(
    const float* __restrict__ in, float4* __restrict__ xQ)
{
    __shared__ float tile[64][65];
    int s  = blockIdx.x >> 2;
    int f0 = (blockIdx.x & 3) * 64;
    int lane = threadIdx.x & 63;
    int r0   = threadIdx.x >> 6;
    for (int r = r0; r < 64; r += 4)
        tile[r][lane] = in[(size_t)r * (512 * 256) + s * 256 + f0 + lane];
    __syncthreads();
    for (int q = r0; q < 16; q += 4) {
        float4 vv = make_float4(tile[lane][4*q], tile[lane][4*q+1],
                                tile[lane][4*q+2], tile[lane][4*q+3]);
        xQ[((size_t)s * 64 + (f0 >> 2) + q) * 64 + lane] = vv;
    }
}

// ---- small weight/state transposes; encH slot0 quad-packed ---------------
__global__ __launch_bounds__(256) void k_prep(
    const float* __restrict__ We_p, const float* __restrict__ Wh_p,
    const float* __restrict__ h0,   const float* __restrict__ c0,
    const float* __restrict__ Wa,
    float* __restrict__ We_pT, float* __restrict__ Wh_pT,
    float* __restrict__ encH0, float* __restrict__ cT,
    float* __restrict__ WahT,  float* __restrict__ WaeT)
{
    int idx = blockIdx.x * blockDim.x + threadIdx.x;
    const int total = 32768 * 4 + 4096 * 2;
    for (; idx < total; idx += gridDim.x * blockDim.x) {
        if (idx < 32768) {
            int u = idx >> 6, h = idx & 63;
            We_pT[idx] = We_p[h * 512 + u];
        } else if (idx < 65536) {
            int i2 = idx - 32768; int k = i2 >> 6, i = i2 & 63;
            Wh_pT[i2] = Wh_p[i * 512 + k];
        } else if (idx < 98304) {
            int i2 = idx - 65536; int u = i2 >> 6, b = i2 & 63;
            encH0[(u >> 2) * 256 + b * 4 + (u & 3)] = h0[b * 512 + u];
        } else if (idx < 131072) {
            int i2 = idx - 98304; int u = i2 >> 6, b = i2 & 63;
            cT[i2] = c0[b * 512 + u];
        } else if (idx < 135168) {
            int i2 = idx - 131072; int j = i2 >> 6, i = i2 & 63;
            WahT[i2] = Wa[i * 128 + j];
        } else {
            int i2 = idx - 135168; int h2 = i2 >> 6, h = i2 & 63;
            WaeT[i2] = Wa[h * 128 + 64 + h2];
        }
    }
}

// ---- W_h = Wih_d.Wo[:, :512] + Whh_d ; W_c = Wih_d.Wo[:, 512:] ; b' ------
__global__ __launch_bounds__(256) void k_prep_wcomb(
    const float* __restrict__ Wih, const float* __restrict__ Whh,
    const float* __restrict__ Wo,  const float* __restrict__ bd,
    const float* __restrict__ bo,
    float* __restrict__ Wh, float* __restrict__ Wc, float* __restrict__ bprime)
{
    int r = blockIdx.x;          // 0..2047
    for (int j = threadIdx.x; j < 576; j += 256) {
        float acc = 0.f;
        for (int f = 0; f < 256; ++f)
            acc = fmaf(Wih[r * 256 + f], Wo[f * 576 + j], acc);
        if (j < 512) Wh[(size_t)r * 512 + j] = acc + Whh[(size_t)r * 512 + j];
        else         Wc[(size_t)r * 64 + (j - 512)] = acc;
    }
    if (threadIdx.x == 0) {
        float s = bd[r];
        for (int f = 0; f < 256; ++f)
            s = fmaf(Wih[r * 256 + f], bo[f], s);
        bprime[r] = s;
    }
}

// ---- g0[r][b] = Wih_d . x_last + b_d -------------------------------------
__global__ __launch_bounds__(256) void k_prep_g0(
    const float4* __restrict__ xQlast, const float* __restrict__ Wih,
    const float* __restrict__ bd, float* __restrict__ g0)
{
    int r = blockIdx.x * 4 + ((int)threadIdx.x >> 6);
    int lane = threadIdx.x & 63;
    const float4* Wih4 = (const float4*)Wih;
    float acc = bd[r];
    for (int q = 0; q < 64; ++q) {
        float4 a  = xQlast[q * 64 + lane];
        float4 wv = Wih4[(size_t)r * 64 + q];
        acc = fmaf(a.x, wv.x, acc); acc = fmaf(a.y, wv.y, acc);
        acc = fmaf(a.z, wv.z, acc); acc = fmaf(a.w, wv.w, acc);
    }
    g0[(size_t)r * 64 + lane] = acc;
}

// ---- gate-GEMM accumulation, register-prefetched (one unit-pair) ---------
// Weight addresses SGPR-derived on purpose (R17: s_load K$ broadcast wins).
template<int NQ>
__device__ __forceinline__ void accum_seg_pf(
    float acc[8], const float4* __restrict__ actQ, int qb,
    const float4* __restrict__ W4, int wstride, int u0, int lane)
{
    float4 a[NQ];
    #pragma unroll
    for (int q = 0; q < NQ; ++q)
        a[q] = actQ[(qb + q) * 64 + lane];
    #pragma unroll
    for (int q = 0; q < NQ; ++q) {
        #pragma unroll
        for (int uu = 0; uu < 2; ++uu)
            #pragma unroll
            for (int g = 0; g < 4; ++g) {
                float4 wv = W4[(size_t)(g * 512 + u0 + uu) * wstride + (qb + q)];
                float& A = acc[uu * 4 + g];
                A = fmaf(a[q].x, wv.x, A); A = fmaf(a[q].y, wv.y, A);
                A = fmaf(a[q].z, wv.z, A); A = fmaf(a[q].w, wv.w, A);
            }
    }
}

// ---- encoder h-part: fused data-poll + accumulate ------------------------
// hslab = encH slot t (quad layout [q][b][4] = float2 pairs). Wave w needs
// quads 16w..16w+15; lane b's float2 index = q*128 + b*2 + {0,1}. Each
// producer wrote its float2 with ONE 8B atomic store, so .x != sentinel
// implies the whole pair is valid AND is the data. 4-quad groups keep
// VGPR pressure low; group 0's poll absorbs the latency, later groups
// normally hit first pass.
__device__ __forceinline__ void accum_h_poll(
    float acc[8], const float* __restrict__ hslab, int w,
    const float4* __restrict__ W4, int u0, int lane)
{
    const unsigned long long* hp = (const unsigned long long*)hslab;
    #pragma unroll
    for (int jg = 0; jg < 4; ++jg) {
        unsigned long long uv[8];
        unsigned pend = 0xFFu;
        for (;;) {
            #pragma unroll
            for (int i = 0; i < 8; ++i) {
                if (pend & (1u << i)) {
                    int q = w * 16 + jg * 4 + (i >> 1);
                    unsigned long long x = __hip_atomic_load(
                        &hp[(size_t)q * 128 + lane * 2 + (i & 1)],
                        __ATOMIC_RELAXED, __HIP_MEMORY_SCOPE_AGENT);
                    if ((unsigned)x != H_SENTINEL) {
                        uv[i] = x;
                        pend &= ~(1u << i);
                    }
                }
            }
            if (__all(pend == 0)) break;
            __builtin_amdgcn_s_sleep(1);
        }
        asm volatile("" ::: "memory");
        #pragma unroll
        for (int j = 0; j < 4; ++j) {
            int q = jg * 4 + j;
            union { unsigned long long u; float2 f; } lo, hi;
            lo.u = uv[2 * j]; hi.u = uv[2 * j + 1];
            float ax = lo.f.x, ay = lo.f.y, az = hi.f.x, aw = hi.f.y;
            #pragma unroll
            for (int uu = 0; uu < 2; ++uu)
                #pragma unroll
                for (int g = 0; g < 4; ++g) {
                    float4 wv = W4[(size_t)(g * 512 + u0 + uu) * 128 + (w * 16 + q)];
                    float& A = acc[uu * 4 + g];
                    A = fmaf(ax, wv.x, A); A = fmaf(ay, wv.y, A);
                    A = fmaf(az, wv.z, A); A = fmaf(aw, wv.w, A);
                }
        }
    }
}

// ---- merged two-pair accumulation: acts loaded ONCE (decoder) ------------
template<int NQ>
__device__ __forceinline__ void accum_seg_pf2(
    float accA[8], float accB[8], const float4* __restrict__ actQ, int qb,
    const float4* __restrict__ W4, int wstride, int u0A, int u0B, int lane)
{
    float4 a[NQ];
    #pragma unroll
    for (int q = 0; q < NQ; ++q)
        a[q] = actQ[(qb + q) * 64 + lane];
    #pragma unroll
    for (int q = 0; q < NQ; ++q) {
        #pragma unroll
        for (int uu = 0; uu < 2; ++uu)
            #pragma unroll
            for (int g = 0; g < 4; ++g) {
                float4 wA = W4[(size_t)(g * 512 + u0A + uu) * wstride + (qb + q)];
                float4 wB = W4[(size_t)(g * 512 + u0B + uu) * wstride + (qb + q)];
                float& A = accA[uu * 4 + g];
                float& Bv = accB[uu * 4 + g];
                A = fmaf(a[q].x, wA.x, A); A = fmaf(a[q].y, wA.y, A);
                A = fmaf(a[q].z, wA.z, A); A = fmaf(a[q].w, wA.w, A);
                Bv = fmaf(a[q].x, wB.x, Bv); Bv = fmaf(a[q].y, wB.y, Bv);
                Bv = fmaf(a[q].z, wB.z, Bv); Bv = fmaf(a[q].w, wB.w, Bv);
            }
    }
}

// ---- ctx-part accumulation from pre-combined register quads --------------
__device__ __forceinline__ void accum_ctx_reg(
    float acc[8], float4 c0, float4 c1,
    const float4* __restrict__ Wc4, int u0, int w)
{
    #pragma unroll
    for (int uu = 0; uu < 2; ++uu)
        #pragma unroll
        for (int g = 0; g < 4; ++g) {
            float4 w0 = Wc4[(size_t)(g * 512 + u0 + uu) * 16 + w * 2 + 0];
            float4 w1 = Wc4[(size_t)(g * 512 + u0 + uu) * 16 + w * 2 + 1];
            float& A = acc[uu * 4 + g];
            A = fmaf(c0.x, w0.x, A); A = fmaf(c0.y, w0.y, A);
            A = fmaf(c0.z, w0.z, A); A = fmaf(c0.w, w0.w, A);
            A = fmaf(c1.x, w1.x, A); A = fmaf(c1.y, w1.y, A);
            A = fmaf(c1.z, w1.z, A); A = fmaf(c1.w, w1.w, A);
        }
}

// ---- finish variant 1: additive = per-row vector (bias / b') — encoder ---
__device__ __forceinline__ void lstm_finish_vec(
    int u0, int tid, int w, float acc[8], float2& creg,
    const float* __restrict__ addVec, float* __restrict__ houtSlot, float* smem)
{
    int lane = tid & 63;
    float* part = smem;          // [8][8][64]
    float* gsum = smem + 4096;   // [8][64]
    #pragma unroll
    for (int r = 0; r < 8; ++r)
        part[(w * 8 + r) * 64 + lane] = acc[r];
    __syncthreads();
    {
        int b = tid & 63, r = tid >> 6;
        float s = 0.f;
        #pragma unroll
        for (int ww = 0; ww < 8; ++ww)
            s += part[(ww * 8 + r) * 64 + b];
        gsum[r * 64 + b] = s;
    }
    __syncthreads();
    if (tid < 64) {
        int b = tid;
        float cc[2] = {creg.x, creg.y};
        float hv[2];
        #pragma unroll
        for (int uu = 0; uu < 2; ++uu) {
            int u = u0 + uu;
            float gi = gsum[(uu*4+0)*64 + b] + addVec[u];
            float gf = gsum[(uu*4+1)*64 + b] + addVec[512 + u];
            float gg = gsum[(uu*4+2)*64 + b] + addVec[1024 + u];
            float go = gsum[(uu*4+3)*64 + b] + addVec[1536 + u];
            float si = fsigmoid(gi), sf = fsigmoid(gf), so = fsigmoid(go);
            float tg = ftanh(gg);
            float cn = sf * cc[uu] + si * tg;
            cc[uu] = cn;
            hv[uu] = so * ftanh(cn);
        }
        creg = make_float2(cc[0], cc[1]);
        coh_store2(houtSlot + (u0 >> 2) * 256 + b * 4 + (u0 & 3),
                   make_float2(hv[0], hv[1]));
    }
}

// ---- merged decoder finish: pair A by wave0-threads, pair B by wave1 -----
template<bool ROWADD>
__device__ __forceinline__ void lstm_finish2(
    int u0A, int u0B, int tid, int w, float accA[8], float accB[8],
    float2& creg, const float* __restrict__ addVec,
    const float* __restrict__ addRowB,
    float* __restrict__ houtSlot, float* smem)
{
    int lane = tid & 63;
    float* part = smem;                  // [8][16][64] = 8192 floats
    #pragma unroll
    for (int r = 0; r < 8; ++r)
        part[(w * 16 + r) * 64 + lane] = accA[r];
    #pragma unroll
    for (int r = 0; r < 8; ++r)
        part[(w * 16 + 8 + r) * 64 + lane] = accB[r];
    __syncthreads();
    if (tid < 128) {
        int b  = tid & 63;
        int ps = tid >> 6;               // 0 = pair A, 1 = pair B
        int u0 = ps ? u0B : u0A;
        float cc[2] = {creg.x, creg.y};
        float hv[2];
        #pragma unroll
        for (int uu = 0; uu < 2; ++uu) {
            int u = u0 + uu;
            float gate[4];
            #pragma unroll
            for (int g = 0; g < 4; ++g) {
                int row = ps * 8 + uu * 4 + g;
                float s = 0.f;
                #pragma unroll
                for (int ww = 0; ww < 8; ++ww)
                    s += part[(ww * 16 + row) * 64 + b];
                if (ROWADD) s += addRowB[(size_t)(g * 512 + u) * 64 + b];
                else        s += addVec[g * 512 + u];
                gate[g] = s;
            }
            float si = fsigmoid(gate[0]), sf = fsigmoid(gate[1]);
            float so = fsigmoid(gate[3]);
            float tg = ftanh(gate[2]);
            float cn = sf * cc[uu] + si * tg;
            cc[uu] = cn;
            hv[uu] = so * ftanh(cn);
        }
        creg = make_float2(cc[0], cc[1]);
        coh_store2(houtSlot + (u0 >> 2) * 256 + b * 4 + (u0 & 3),
                   make_float2(hv[0], hv[1]));
        asm volatile("s_waitcnt vmcnt(0)" ::: "memory");  // drain both h-writer waves
    }
    __syncthreads();   // flag post (tid0) ordered after both waves' drains
}

// ---- persistent encoder: data-as-flag dataflow (no flag array) -----------
// Producer h-stores are 8B atomics into sentinel-filled slots; consumers
// poll the exact words they consume (accum_h_poll). No drains, no flags.
__global__ __launch_bounds__(512, 2) void k_enc_persistent(
    const float4* __restrict__ xQ, float* __restrict__ encH,
    float* __restrict__ cT,
    const float* __restrict__ Wih, const float* __restrict__ Whh,
    const float* __restrict__ bias)
{
    __shared__ float smem[4608];
    int tid = threadIdx.x;
    int lane = tid & 63;
    int w = __builtin_amdgcn_readfirstlane(tid >> 6);
    int bi = blockIdx.x;
    int u0 = bi * 2;
    const float4* Wih4 = (const float4*)Wih;
    const float4* Whh4 = (const float4*)Whh;
    float2 creg = make_float2(0.f, 0.f);
    if (tid < 64) { creg.x = cT[u0 * 64 + tid]; creg.y = cT[(u0 + 1) * 64 + tid]; }
    float acc[8];
    #pragma unroll
    for (int r = 0; r < 8; ++r) acc[r] = 0.f;
    accum_seg_pf<8>(acc, xQ, w * 8, Wih4, 64, u0, lane);       // x-part t=0
    for (int t = 0; t < 512; ++t) {
        accum_h_poll(acc, encH + (size_t)t * 32768, w, Whh4, u0, lane);
        lstm_finish_vec(u0, tid, w, acc, creg, bias,
                        encH + (size_t)(t + 1) * 32768, smem);
        #pragma unroll
        for (int r = 0; r < 8; ++r) acc[r] = 0.f;
        if (t + 1 < 512)   // x-part t+1 overlaps others' tail; stride 4096 f4
            accum_seg_pf<8>(acc, xQ + (size_t)(t + 1) * 4096, w * 8, Wih4, 64, u0, lane);
    }
    if (tid < 64) { cT[u0 * 64 + tid] = creg.x; cT[(u0 + 1) * 64 + tid] = creg.y; }
}

// ---- enc_proj + enc_attn (ba folded), round-5 form -----------------------
__global__ __launch_bounds__(256) void k_proj_attn(
    const float* __restrict__ encH,  const float* __restrict__ We_pT,
    const float* __restrict__ be_p,  const float* __restrict__ WaeT,
    const float* __restrict__ ba,
    float* __restrict__ encProj, float* __restrict__ attnPre)
{
    int lane = threadIdx.x & 63;
    int w    = __builtin_amdgcn_readfirstlane((int)threadIdx.x >> 6);
    int wid  = blockIdx.x * 4 + w;
    int b    = wid >> 6;
    int soct = wid & 63;
    float acc[8];
    float bep = be_p[lane];
    #pragma unroll
    for (int j = 0; j < 8; ++j) acc[j] = bep;
    #pragma unroll 2
    for (int q = 0; q < 128; ++q) {
        float w0 = We_pT[(4*q+0) * 64 + lane];
        float w1 = We_pT[(4*q+1) * 64 + lane];
        float w2 = We_pT[(4*q+2) * 64 + lane];
        float w3 = We_pT[(4*q+3) * 64 + lane];
        #pragma unroll
        for (int j = 0; j < 8; ++j) {
            const float4* hb4 = (const float4*)(encH + (size_t)(soct*8 + j + 1) * 32768);
            float4 hv = hb4[q * 64 + b];
            acc[j] = fmaf(hv.x, w0, acc[j]); acc[j] = fmaf(hv.y, w1, acc[j]);
            acc[j] = fmaf(hv.z, w2, acc[j]); acc[j] = fmaf(hv.w, w3, acc[j]);
        }
    }
    #pragma unroll
    for (int j = 0; j < 8; ++j)
        encProj[((size_t)b * 512 + soct * 8 + j) * 64 + lane] = acc[j];
    #pragma unroll
    for (int j = 0; j < 8; ++j) {
        float aa = ba[lane];
        for (int h2 = 0; h2 < 64; ++h2)
            aa = fmaf(__shfl(acc[j], h2), WaeT[h2 * 64 + lane], aa);
        attnPre[((size_t)b * 512 + soct * 8 + j) * 64 + lane] = aa;
    }
}

// ---- attnPre [b][s][h] -> attnPreT [b][h][s] (tile transpose) ------------
__global__ __launch_bounds__(256) void k_attn_transpose(
    const float* __restrict__ attnPre, float* __restrict__ attnPreT)
{
    __shared__ float tile[64][65];
    int b  = blockIdx.x >> 3;        // 0..63
    int s0 = (blockIdx.x & 7) * 64;  // 0..448
    int lane = threadIdx.x & 63;
    int r0   = threadIdx.x >> 6;
    for (int r = r0; r < 64; r += 4)
        tile[r][lane] = attnPre[(size_t)b * 32768 + (size_t)(s0 + r) * 64 + lane];
    __syncthreads();
    for (int r = r0; r < 64; r += 4)
        attnPreT[(size_t)b * 32768 + (size_t)r * 512 + s0 + lane] = tile[lane][r];
}

// ---- attention HALF for batch b (LDS-resident ap/ep slices) --------------
__device__ __forceinline__ void attention_half(
    int b, int tid, int w, int lane,
    const float* __restrict__ hcur,     // quad-packed h (full)
    const float* __restrict__ Wh_pT, const float* __restrict__ bh_p,
    const float* __restrict__ WahT,  const float* __restrict__ v,
    const float* __restrict__ apL,      // LDS [64][256]
    const float* __restrict__ epL,      // LDS [256][64]
    float* __restrict__ ctxsumOut,      // quad-packed (4096)
    float* __restrict__ mSOut,          // [0..63]=m, [64..127]=S per b
    float* smem)
{
    float* hq  = smem;          // 64
    float* hWa = smem + 64;     // 64
    float* sc  = smem + 128;    // 256
    float* part = smem + 384;   // 512
    float* red  = smem + 896;   // 16
    {
        const float4* h4 = (const float4*)hcur;
        float4 hv[16];
        #pragma unroll
        for (int j = 0; j < 16; ++j)
            hv[j] = h4[(w * 16 + j) * 64 + b];
        float p = 0.f;
        #pragma unroll
        for (int j = 0; j < 16; ++j) {
            int q = w * 16 + j;
            p = fmaf(hv[j].x, Wh_pT[(4*q+0) * 64 + lane], p);
            p = fmaf(hv[j].y, Wh_pT[(4*q+1) * 64 + lane], p);
            p = fmaf(hv[j].z, Wh_pT[(4*q+2) * 64 + lane], p);
            p = fmaf(hv[j].w, Wh_pT[(4*q+3) * 64 + lane], p);
        }
        part[w * 64 + lane] = p;
    }
    __syncthreads();
    if (tid < 64) {
        float s = bh_p[tid];
        #pragma unroll
        for (int ww = 0; ww < 8; ++ww) s += part[ww * 64 + tid];
        hq[tid] = s;
    }
    __syncthreads();
    if (tid < 64) {
        float s = 0.f;
        for (int j = 0; j < 64; ++j)
            s = fmaf(hq[j], WahT[j * 64 + tid], s);
        hWa[tid] = s;
    }
    __syncthreads();
    {
        int sp  = tid & 255;
        int hh0 = (tid >> 8) * 32;
        float acc = 0.f;
        for (int j = 0; j < 32; ++j) {
            int h = hh0 + j;
            float e = ftanh(hWa[h] + apL[h * 256 + sp]);
            acc = fmaf(v[h], e, acc);
        }
        part[tid] = acc;
    }
    __syncthreads();
    if (tid < 256)
        sc[tid] = part[tid] + part[256 + tid];
    __syncthreads();
    if (tid < 256) {
        float x = sc[tid];
        float m = x;
        #pragma unroll
        for (int off = 32; off > 0; off >>= 1)
            m = fmaxf(m, __shfl_xor(m, off));
        if (lane == 0) red[w] = m;
    }
    __syncthreads();
    if (tid == 0)
        red[8] = fmaxf(fmaxf(red[0], red[1]), fmaxf(red[2], red[3]));
    __syncthreads();
    float M = red[8];
    if (tid < 256) {
        float e = __expf(sc[tid] - M);
        sc[tid] = e;
        float s = e;
        #pragma unroll
        for (int off = 32; off > 0; off >>= 1)
            s += __shfl_xor(s, off);
        if (lane == 0) red[w] = s;
    }
    __syncthreads();
    if (tid == 0)
        red[9] = ((red[0] + red[1]) + (red[2] + red[3]));
    __syncthreads();
    {
        float a = 0.f;
        for (int i = 0; i < 32; ++i) {
            int sp2 = w * 32 + i;
            a = fmaf(sc[sp2], epL[sp2 * 64 + lane], a);
        }
        part[w * 64 + lane] = a;
    }
    __syncthreads();
    if (tid < 64) {
        float s = 0.f;
        #pragma unroll
        for (int ww = 0; ww < 8; ++ww) s += part[ww * 64 + tid];
        coh_store(&ctxsumOut[(tid >> 2) * 256 + b * 4 + (tid & 3)], s);
    }
    if (tid == 0) {
        coh_store(&mSOut[b], M);
        coh_store(&mSOut[64 + b], red[9]);
    }
    __syncthreads();
}

// ---- combined ctx quads for a wave (lane = b) ----------------------------
__device__ __forceinline__ void load_ctx_quads(
    int t, int w, int lane,
    const float* __restrict__ ctxsumH, const float* __restrict__ mSbuf,
    float4& c0, float4& c1)
{
    const float* mS = mSbuf + (size_t)(t - 1) * 256;
    float m0 = mS[lane],       S0 = mS[64 + lane];
    float m1 = mS[128 + lane], S1 = mS[192 + lane];
    float M  = fmaxf(m0, m1);
    float e0 = __expf(m0 - M), e1 = __expf(m1 - M);
    float inv = 1.0f / (e0 * S0 + e1 * S1);
    e0 *= inv; e1 *= inv;
    const float4* a0 = (const float4*)(ctxsumH + (size_t)(t - 1) * 8192);
    const float4* a1 = (const float4*)(ctxsumH + (size_t)(t - 1) * 8192 + 4096);
    float4 x0 = a0[(w * 2 + 0) * 64 + lane];
    float4 y0 = a1[(w * 2 + 0) * 64 + lane];
    float4 x1 = a0[(w * 2 + 1) * 64 + lane];
    float4 y1 = a1[(w * 2 + 1) * 64 + lane];
    c0 = make_float4(e0 * x0.x + e1 * y0.x, e0 * x0.y + e1 * y0.y,
                     e0 * x0.z + e1 * y0.z, e0 * x0.w + e1 * y0.w);
    c1 = make_float4(e0 * x1.x + e1 * y1.x, e0 * x1.y + e1 * y1.y,
                     e0 * x1.z + e1 * y1.z, e0 * x1.w + e1 * y1.w);
}

// ---- persistent decoder: 128 attn-half blocks + 128 LSTM blocks ----------
// Dynamic LDS layout (149504 B): scratch@0 (attn 4608 / lstm part 8192 —
// DISJOINT block roles) | apL@4608 (16384) | epL@20992 (16384).
// attnFlagsR/lstmFlagsR: 8 replicas x 128 words each (R19 contention win).
extern __shared__ float dynsmem[];
__global__ __launch_bounds__(512) void k_dec_persistent(
    const float* __restrict__ encHend,
    float* __restrict__ dechH,            // [96][quad 32768]
    float* __restrict__ cT,
    const float* __restrict__ Whh,        // t=0 h-part
    const float* __restrict__ Wh,         // t>=1 fused h-part
    const float* __restrict__ Wc,         // ctx part
    const float* __restrict__ g0, const float* __restrict__ bprime,
    const float* __restrict__ Wh_pT, const float* __restrict__ bh_p,
    const float* __restrict__ WahT,  const float* __restrict__ v,
    const float* __restrict__ attnPreT, const float* __restrict__ encProj,
    float* __restrict__ ctxsumH,          // [96][2][4096]
    float* __restrict__ mSbuf,            // [96][256]
    unsigned* attnFlagsR, unsigned* lstmFlagsR)
{
    float* smem = dynsmem;                // attn scratch 4608 / lstm part 8192
    float* apL  = dynsmem + 4608;         // 16384: [h][s']   (attn only)
    float* epL  = apL + 16384;            // 16384: [s'][h2]  (attn only)
    int tid = threadIdx.x;
    int lane = tid & 63;
    int w = __builtin_amdgcn_readfirstlane(tid >> 6);
    int bi = blockIdx.x;
    int rep = bi & 7;
    const unsigned* myLstmF = lstmFlagsR + rep * 128;
    const unsigned* myAttnF = attnFlagsR + rep * 128;
    if (bi < 128) {
        int b = bi & 63, half = bi >> 6;
        {
            const float4* src = (const float4*)(attnPreT + (size_t)b * 32768 + half * 256);
            float4* dst = (float4*)apL;
            for (int i = tid; i < 4096; i += 512) {
                int h = i >> 6, qc = i & 63;
                dst[i] = src[(size_t)h * 128 + qc];
            }
        }
        {
            const float4* src = (const float4*)(encProj + ((size_t)b * 512 + half * 256) * 64);
            float4* dst = (float4*)epL;
            for (int i = tid; i < 4096; i += 512)
                dst[i] = src[i];
        }
        __syncthreads();
        for (int t = 0; t < 96; ++t) {
            if (t) wait_group(myLstmF, (w & 3) * 32, 31, (unsigned)t);
            const float* hc = t ? dechH + (size_t)(t - 1) * 32768 : encHend;
            attention_half(b, tid, w, lane, hc, Wh_pT, bh_p, WahT, v,
                           apL, epL,
                           ctxsumH + (size_t)t * 8192 + half * 4096,
                           mSbuf + (size_t)t * 256 + half * 128, smem);
            post_flag_rep(attnFlagsR, 128, bi, (unsigned)(t + 1));
        }
    } else {
        int u0A = (bi - 128) * 2;
        int u0B = u0A + 256;
        const float4* Whh4 = (const float4*)Whh;
        const float4* Wh4  = (const float4*)Wh;
        const float4* Wc4  = (const float4*)Wc;
        // c-state: wave0 threads hold pair A, wave1 threads hold pair B.
        float2 creg = make_float2(0.f, 0.f);
        if (tid < 64) {
            creg.x = cT[u0A * 64 + tid]; creg.y = cT[(u0A + 1) * 64 + tid];
        } else if (tid < 128) {
            creg.x = cT[u0B * 64 + (tid - 64)];
            creg.y = cT[(u0B + 1) * 64 + (tid - 64)];
        }
        for (int t = 0; t < 96; ++t) {
            if (t) wait_lstm_inputs(myAttnF, myLstmF, w, (unsigned)t);
            const float* hc = t ? dechH + (size_t)(t - 1) * 32768 : encHend;
            float* hn = dechH + (size_t)t * 32768;
            float accA[8], accB[8];
            #pragma unroll
            for (int r = 0; r < 8; ++r) { accA[r] = 0.f; accB[r] = 0.f; }
            if (t == 0) {
                accum_seg_pf2<16>(accA, accB, (const float4*)hc, w * 16,
                                  Whh4, 128, u0A, u0B, lane);
                lstm_finish2<true>(u0A, u0B, tid, w, accA, accB, creg,
                                   nullptr, g0, hn, smem);
            } else {
                float4 cq0, cq1;
                load_ctx_quads(t, w, lane, ctxsumH, mSbuf, cq0, cq1);
                accum_seg_pf2<16>(accA, accB, (const float4*)hc, w * 16,
                                  Wh4, 128, u0A, u0B, lane);
                accum_ctx_reg(accA, cq0, cq1, Wc4, u0A, w);
                accum_ctx_reg(accB, cq0, cq1, Wc4, u0B, w);
                lstm_finish2<false>(u0A, u0B, tid, w, accA, accB, creg,
                                    bprime, nullptr, hn, smem);
            }
            post_flag_rep(lstmFlagsR, 128, bi - 128, (unsigned)(t + 1));
        }
    }
}

// ---- post-pass: dout[b][tau] = Wo[255].[h^{(tau+1)}; ctx_tau] + bo[255] --
__global__ __launch_bounds__(256) void k_dout(
    const float* __restrict__ dechH,
    const float* __restrict__ ctxsumH, const float* __restrict__ mSbuf,
    const float* __restrict__ Wo, const float* __restrict__ bo,
    float* __restrict__ dout)
{
    __shared__ float part[256];
    int tau = blockIdx.x;            // 0..95
    int tid = threadIdx.x;
    int lane = tid & 63;             // = b
    int w = tid >> 6;                // 0..3
    const float* hq = dechH + (size_t)tau * 32768;
    const float* wrow = Wo + 255 * 576;
    float acc = 0.f;
    for (int i = w * 128; i < w * 128 + 128; ++i)
        acc = fmaf(wrow[i], hq[(i >> 2) * 256 + lane * 4 + (i & 3)], acc);
    part[w * 64 + lane] = acc;
    __syncthreads();
    if (tid < 64) {
        int b = tid;
        const float* mS = mSbuf + (size_t)tau * 256;
        float m0 = mS[b],       S0 = mS[64 + b];
        float m1 = mS[128 + b], S1 = mS[192 + b];
        float M  = fmaxf(m0, m1);
        float e0 = __expf(m0 - M), e1 = __expf(m1 - M);
        float inv = 1.0f / (e0 * S0 + e1 * S1);
        e0 *= inv; e1 *= inv;
        const float* cs0 = ctxsumH + (size_t)tau * 8192;
        const float* cs1 = cs0 + 4096;
        float a2 = bo[255];
        for (int h2 = 0; h2 < 64; ++h2) {
            int idx = (h2 >> 2) * 256 + b * 4 + (h2 & 3);
            a2 = fmaf(wrow[512 + h2], e0 * cs0[idx] + e1 * cs1[idx], a2);
        }
        float s = a2 + part[b] + part[64 + b] + part[128 + b] + part[192 + b];
        dout[b * 96 + tau] = s;
    }
}

} // namespace

extern "C" void kernel_launch(void* const* d_in, const int* in_sizes, int n_in,
                              void* d_out, int out_size, void* d_ws, size_t ws_size,
                              hipStream_t stream)
{
    (void)in_sizes; (void)n_in; (void)out_size; (void)ws_size;
    const float* input_seq = (const float*)d_in[0];
    const float* h0     = (const float*)d_in[1];
    const float* c0     = (const float*)d_in[2];
    const float* W_ih_e = (const float*)d_in[3];
    const float* W_hh_e = (const float*)d_in[4];
    const float* b_e    = (const float*)d_in[5];
    const float* W_ih_d = (const float*)d_in[6];
    const float* W_hh_d = (const float*)d_in[7];
    const float* b_d    = (const float*)d_in[8];
    const float* We_p   = (const float*)d_in[9];
    const float* be_p   = (const float*)d_in[10];
    const float* Wh_p   = (const float*)d_in[11];
    const float* bh_p   = (const float*)d_in[12];
    const float* Wa     = (const float*)d_in[13];
    const float* ba     = (const float*)d_in[14];
    const float* v      = (const float*)d_in[15];
    const float* Wo     = (const float*)d_in[16];
    const float* bo     = (const float*)d_in[17];
    float* out = (float*)d_out;

    // Flag replicas (decoder only): attn 8x128 | lstm 8x128 = 2048 words.
    unsigned* attnFlagsR = (unsigned*)d_ws;     // [8][128]
    unsigned* lstmFlagsR = attnFlagsR + 1024;   // [8][128]
    float* ws       = (float*)d_ws + 4096;      // 16KB offset
    float* xT       = ws;                       // 8388608 (dead after enc/g0)
    float* encH     = xT + 8388608;             // 513*32768 = 16809984
    float* cT       = encH + 16809984;          // 32768
    float* We_pT    = cT + 32768;               // 32768
    float* Wh_pT    = We_pT + 32768;            // 32768
    float* WahT     = Wh_pT + 32768;            // 4096
    float* WaeT     = WahT + 4096;              // 4096
    float* encProj  = WaeT + 4096;              // 2097152
    float* attnPre  = encProj + 2097152;        // 2097152
    float* dechH    = attnPre + 2097152;        // 96*32768 = 3145728
    float* ctxsumH  = dechH + 3145728;          // 96*2*4096 = 786432
    float* mSbuf    = ctxsumH + 786432;         // 96*256 = 24576
    float* Wh       = mSbuf + 24576;            // 2048*512 = 1048576
    float* Wc       = Wh + 1048576;             // 2048*64 = 131072
    float* bprime   = Wc + 131072;              // 2048
    float* g0       = bprime + 2048;            // 2048*64 = 131072
    float* attnPreT = xT;                       // aliases dead xT region (2M)

    (void)hipFuncSetAttribute((const void*)k_dec_persistent,
                              hipFuncAttributeMaxDynamicSharedMemorySize, 149504);

    (void)hipMemsetAsync(d_ws, 0, 16384, stream);  // zero decoder flag replicas
    // Sentinel-fill encH slots 1..512 (slot 0 is written by k_prep):
    // byte 0x7F -> float 0x7F7F7F7F = 3.4e38, unreachable by |h|<1.
    (void)hipMemsetAsync(encH + 32768, 0x7F, (size_t)512 * 32768 * 4, stream);
    k_transpose_input<<<2048, 256, 0, stream>>>(input_seq, (float4*)xT);
    k_prep<<<544, 256, 0, stream>>>(We_p, Wh_p, h0, c0, Wa,
                                    We_pT, Wh_pT, encH, cT, WahT, WaeT);
    k_prep_wcomb<<<2048, 256, 0, stream>>>(W_ih_d, W_hh_d, Wo, b_d, bo,
                                           Wh, Wc, bprime);
    k_prep_g0<<<512, 256, 0, stream>>>((const float4*)(xT + (size_t)511 * 16384),
                                       W_ih_d, b_d, g0);
    k_enc_persistent<<<256, 512, 0, stream>>>((const float4*)xT, encH, cT,
                                              W_ih_e, W_hh_e, b_e);
    k_proj_attn<<<1024, 256, 0, stream>>>(encH, We_pT, be_p, WaeT, ba,
                                          encProj, attnPre);
    k_attn_transpose<<<512, 256, 0, stream>>>(attnPre, attnPreT);
    k_dec_persistent<<<256, 512, 149504, stream>>>(encH + (size_t)512 * 32768,
                                                   dechH, cT,
                                                   W_hh_d, Wh, Wc, g0, bprime,
                                                   Wh_pT, bh_p, WahT, v,
                                                   attnPreT, encProj,
                                                   ctxsumH, mSbuf,
                                                   attnFlagsR, lstmFlagsR);
    k_dout<<<96, 256, 0, stream>>>(dechH, ctxsumH, mSbuf, Wo, bo, out);
}

// Round 11
// 5425.664 us; speedup vs baseline: 1.7253x; 1.7253x over previous
//
#include <hip/hip_runtime.h>

// Seq2seq LSTM + attention — persistent kernels, ROUND-21: R19 + prep-fold.
//
// Ledger: R12 dataflow 5735. R15/16 dec merge 5574. R19 flag replication
// 5239 = BEST (dec contention win; enc null). R20 data-as-flag REGRESS 2.3x:
// polling data words turns the coalesced cached h-stream into uncoalesced
// 8B coherent atomic loads — bulk data must stay on the fast path, signal
// with one flag line. Encoder sync chain = topology floor (R13/14/17/19e/20
// all null-or-worse).
//
// R21: exact R19 base + fold k_prep_wcomb/k_prep_g0 into the encoder's
// idle spin windows (VALUBusy 42% incl spin -> ~75% idle per 6.3us step).
// Block bi does wcomb rows 8bi..8bi+7 at t=0..7 (after post_flag_rep, so
// the h critical chain is untouched; j=tid keeps Wo reads coalesced) and
// g0 rows at t=8..15 (partials in the dead gsum LDS region; sync before
// write [finish(t) epilogue readers] — trailing hazard covered by
// finish(t+1)'s own barrier waiting on wave0). Outputs only read by the
// decoder kernel (launched after enc completes -> kernel-boundary
// coherence, same as the standalone kernels relied on). Grid stays 256:
// no dispatch-order assumption, no deadlock risk.
// Predict: wcomb/g0 dispatches gone, enc <= ~3350, total ~4950-5150,
// absmax 0.0. Null => prep was cheaper than estimated; plateau accepted.

namespace {

__device__ __forceinline__ float fsigmoid(float x) {
    return 1.0f / (1.0f + __expf(-x));
}
__device__ __forceinline__ float ftanh(float x) {
    float e = __expf(2.0f * x);
    return 1.0f - 2.0f / (e + 1.0f);
}

__device__ __forceinline__ void coh_store(float* p, float v) {
    __hip_atomic_store(p, v, __ATOMIC_RELAXED, __HIP_MEMORY_SCOPE_AGENT);
}
__device__ __forceinline__ void coh_store2(float* p, float2 v) {
    union { float2 f; unsigned long long u; } cv; cv.f = v;
    __hip_atomic_store((unsigned long long*)p, cv.u,
                       __ATOMIC_RELAXED, __HIP_MEMORY_SCOPE_AGENT);
}

// ---- replicated dataflow flags (R19 contention win) ----------------------
__device__ __forceinline__ void post_flag_rep(unsigned* flags, int stride,
                                              int idx, unsigned val) {
    if (threadIdx.x == 0) {
        asm volatile("s_waitcnt vmcnt(0)" ::: "memory");
        #pragma unroll
        for (int r = 0; r < 8; ++r)
            __hip_atomic_store(&flags[r * stride + idx], val,
                               __ATOMIC_RELAXED, __HIP_MEMORY_SCOPE_AGENT);
    }
}
__device__ __forceinline__ void wait_group(const unsigned* flags, int base,
                                           int mask, unsigned val) {
    const unsigned* f = flags + base + (threadIdx.x & mask);
    for (;;) {
        unsigned x = __hip_atomic_load(f, __ATOMIC_RELAXED, __HIP_MEMORY_SCOPE_AGENT);
        if (__all(x >= val)) break;
        __builtin_amdgcn_s_sleep(1);
    }
    asm volatile("" ::: "memory");   // no hoisting of data loads above poll
}
__device__ __forceinline__ void wait_lstm_inputs(const unsigned* attnF,
                                                 const unsigned* lstmF,
                                                 int w, unsigned val) {
    int lane = threadIdx.x & 63;
    const unsigned* fa = attnF + lane * 2;
    const unsigned* fl = lstmF + (w & 3) * 32 + (lane & 31);
    for (;;) {
        unsigned a = __hip_atomic_load(fa + 0, __ATOMIC_RELAXED, __HIP_MEMORY_SCOPE_AGENT);
        unsigned b = __hip_atomic_load(fa + 1, __ATOMIC_RELAXED, __HIP_MEMORY_SCOPE_AGENT);
        unsigned c = __hip_atomic_load(fl,     __ATOMIC_RELAXED, __HIP_MEMORY_SCOPE_AGENT);
        int ok = (a >= val) && (b >= val) && (c >= val);
        if (__all(ok)) break;
        __builtin_amdgcn_s_sleep(1);
    }
    asm volatile("" ::: "memory");
}

// ---- transpose input_seq (B,S,F) -> quad layout [s][f/4][b][4] -----------
__global__ __launch_bounds__(256) void k_transpose_input(
    const float* __restrict__ in, float4* __restrict__ xQ)
{
    __shared__ float tile[64][65];
    int s  = blockIdx.x >> 2;
    int f0 = (blockIdx.x & 3) * 64;
    int lane = threadIdx.x & 63;
    int r0   = threadIdx.x >> 6;
    for (int r = r0; r < 64; r += 4)
        tile[r][lane] = in[(size_t)r * (512 * 256) + s * 256 + f0 + lane];
    __syncthreads();
    for (int q = r0; q < 16; q += 4) {
        float4 vv = make_float4(tile[lane][4*q], tile[lane][4*q+1],
                                tile[lane][4*q+2], tile[lane][4*q+3]);
        xQ[((size_t)s * 64 + (f0 >> 2) + q) * 64 + lane] = vv;
    }
}

// ---- small weight/state transposes; encH slot0 quad-packed ---------------
__global__ __launch_bounds__(256) void k_prep(
    const float* __restrict__ We_p, const float* __restrict__ Wh_p,
    const float* __restrict__ h0,   const float* __restrict__ c0,
    const float* __restrict__ Wa,
    float* __restrict__ We_pT, float* __restrict__ Wh_pT,
    float* __restrict__ encH0, float* __restrict__ cT,
    float* __restrict__ WahT,  float* __restrict__ WaeT)
{
    int idx = blockIdx.x * blockDim.x + threadIdx.x;
    const int total = 32768 * 4 + 4096 * 2;
    for (; idx < total; idx += gridDim.x * blockDim.x) {
        if (idx < 32768) {
            int u = idx >> 6, h = idx & 63;
            We_pT[idx] = We_p[h * 512 + u];
        } else if (idx < 65536) {
            int i2 = idx - 32768; int k = i2 >> 6, i = i2 & 63;
            Wh_pT[i2] = Wh_p[i * 512 + k];
        } else if (idx < 98304) {
            int i2 = idx - 65536; int u = i2 >> 6, b = i2 & 63;
            encH0[(u >> 2) * 256 + b * 4 + (u & 3)] = h0[b * 512 + u];
        } else if (idx < 131072) {
            int i2 = idx - 98304; int u = i2 >> 6, b = i2 & 63;
            cT[i2] = c0[b * 512 + u];
        } else if (idx < 135168) {
            int i2 = idx - 131072; int j = i2 >> 6, i = i2 & 63;
            WahT[i2] = Wa[i * 128 + j];
        } else {
            int i2 = idx - 135168; int h2 = i2 >> 6, h = i2 & 63;
            WaeT[i2] = Wa[h * 128 + 64 + h2];
        }
    }
}

// ---- gate-GEMM accumulation, register-prefetched (one unit-pair) ---------
// Weight addresses SGPR-derived on purpose (R17: s_load K$ broadcast wins).
template<int NQ>
__device__ __forceinline__ void accum_seg_pf(
    float acc[8], const float4* __restrict__ actQ, int qb,
    const float4* __restrict__ W4, int wstride, int u0, int lane)
{
    float4 a[NQ];
    #pragma unroll
    for (int q = 0; q < NQ; ++q)
        a[q] = actQ[(qb + q) * 64 + lane];
    #pragma unroll
    for (int q = 0; q < NQ; ++q) {
        #pragma unroll
        for (int uu = 0; uu < 2; ++uu)
            #pragma unroll
            for (int g = 0; g < 4; ++g) {
                float4 wv = W4[(size_t)(g * 512 + u0 + uu) * wstride + (qb + q)];
                float& A = acc[uu * 4 + g];
                A = fmaf(a[q].x, wv.x, A); A = fmaf(a[q].y, wv.y, A);
                A = fmaf(a[q].z, wv.z, A); A = fmaf(a[q].w, wv.w, A);
            }
    }
}

// ---- merged two-pair accumulation: acts loaded ONCE (decoder) ------------
template<int NQ>
__device__ __forceinline__ void accum_seg_pf2(
    float accA[8], float accB[8], const float4* __restrict__ actQ, int qb,
    const float4* __restrict__ W4, int wstride, int u0A, int u0B, int lane)
{
    float4 a[NQ];
    #pragma unroll
    for (int q = 0; q < NQ; ++q)
        a[q] = actQ[(qb + q) * 64 + lane];
    #pragma unroll
    for (int q = 0; q < NQ; ++q) {
        #pragma unroll
        for (int uu = 0; uu < 2; ++uu)
            #pragma unroll
            for (int g = 0; g < 4; ++g) {
                float4 wA = W4[(size_t)(g * 512 + u0A + uu) * wstride + (qb + q)];
                float4 wB = W4[(size_t)(g * 512 + u0B + uu) * wstride + (qb + q)];
                float& A = accA[uu * 4 + g];
                float& Bv = accB[uu * 4 + g];
                A = fmaf(a[q].x, wA.x, A); A = fmaf(a[q].y, wA.y, A);
                A = fmaf(a[q].z, wA.z, A); A = fmaf(a[q].w, wA.w, A);
                Bv = fmaf(a[q].x, wB.x, Bv); Bv = fmaf(a[q].y, wB.y, Bv);
                Bv = fmaf(a[q].z, wB.z, Bv); Bv = fmaf(a[q].w, wB.w, Bv);
            }
    }
}

// ---- ctx-part accumulation from pre-combined register quads --------------
__device__ __forceinline__ void accum_ctx_reg(
    float acc[8], float4 c0, float4 c1,
    const float4* __restrict__ Wc4, int u0, int w)
{
    #pragma unroll
    for (int uu = 0; uu < 2; ++uu)
        #pragma unroll
        for (int g = 0; g < 4; ++g) {
            float4 w0 = Wc4[(size_t)(g * 512 + u0 + uu) * 16 + w * 2 + 0];
            float4 w1 = Wc4[(size_t)(g * 512 + u0 + uu) * 16 + w * 2 + 1];
            float& A = acc[uu * 4 + g];
            A = fmaf(c0.x, w0.x, A); A = fmaf(c0.y, w0.y, A);
            A = fmaf(c0.z, w0.z, A); A = fmaf(c0.w, w0.w, A);
            A = fmaf(c1.x, w1.x, A); A = fmaf(c1.y, w1.y, A);
            A = fmaf(c1.z, w1.z, A); A = fmaf(c1.w, w1.w, A);
        }
}

// ---- finish variant 1: additive = per-row vector (bias / b') — encoder ---
__device__ __forceinline__ void lstm_finish_vec(
    int u0, int tid, int w, float acc[8], float2& creg,
    const float* __restrict__ addVec, float* __restrict__ houtSlot, float* smem)
{
    int lane = tid & 63;
    float* part = smem;          // [8][8][64]
    float* gsum = smem + 4096;   // [8][64]
    #pragma unroll
    for (int r = 0; r < 8; ++r)
        part[(w * 8 + r) * 64 + lane] = acc[r];
    __syncthreads();
    {
        int b = tid & 63, r = tid >> 6;
        float s = 0.f;
        #pragma unroll
        for (int ww = 0; ww < 8; ++ww)
            s += part[(ww * 8 + r) * 64 + b];
        gsum[r * 64 + b] = s;
    }
    __syncthreads();
    if (tid < 64) {
        int b = tid;
        float cc[2] = {creg.x, creg.y};
        float hv[2];
        #pragma unroll
        for (int uu = 0; uu < 2; ++uu) {
            int u = u0 + uu;
            float gi = gsum[(uu*4+0)*64 + b] + addVec[u];
            float gf = gsum[(uu*4+1)*64 + b] + addVec[512 + u];
            float gg = gsum[(uu*4+2)*64 + b] + addVec[1024 + u];
            float go = gsum[(uu*4+3)*64 + b] + addVec[1536 + u];
            float si = fsigmoid(gi), sf = fsigmoid(gf), so = fsigmoid(go);
            float tg = ftanh(gg);
            float cn = sf * cc[uu] + si * tg;
            cc[uu] = cn;
            hv[uu] = so * ftanh(cn);
        }
        creg = make_float2(cc[0], cc[1]);
        coh_store2(houtSlot + (u0 >> 2) * 256 + b * 4 + (u0 & 3),
                   make_float2(hv[0], hv[1]));
    }
}

// ---- merged decoder finish: pair A by wave0-threads, pair B by wave1 -----
template<bool ROWADD>
__device__ __forceinline__ void lstm_finish2(
    int u0A, int u0B, int tid, int w, float accA[8], float accB[8],
    float2& creg, const float* __restrict__ addVec,
    const float* __restrict__ addRowB,
    float* __restrict__ houtSlot, float* smem)
{
    int lane = tid & 63;
    float* part = smem;                  // [8][16][64] = 8192 floats
    #pragma unroll
    for (int r = 0; r < 8; ++r)
        part[(w * 16 + r) * 64 + lane] = accA[r];
    #pragma unroll
    for (int r = 0; r < 8; ++r)
        part[(w * 16 + 8 + r) * 64 + lane] = accB[r];
    __syncthreads();
    if (tid < 128) {
        int b  = tid & 63;
        int ps = tid >> 6;               // 0 = pair A, 1 = pair B
        int u0 = ps ? u0B : u0A;
        float cc[2] = {creg.x, creg.y};
        float hv[2];
        #pragma unroll
        for (int uu = 0; uu < 2; ++uu) {
            int u = u0 + uu;
            float gate[4];
            #pragma unroll
            for (int g = 0; g < 4; ++g) {
                int row = ps * 8 + uu * 4 + g;
                float s = 0.f;
                #pragma unroll
                for (int ww = 0; ww < 8; ++ww)
                    s += part[(ww * 16 + row) * 64 + b];
                if (ROWADD) s += addRowB[(size_t)(g * 512 + u) * 64 + b];
                else        s += addVec[g * 512 + u];
                gate[g] = s;
            }
            float si = fsigmoid(gate[0]), sf = fsigmoid(gate[1]);
            float so = fsigmoid(gate[3]);
            float tg = ftanh(gate[2]);
            float cn = sf * cc[uu] + si * tg;
            cc[uu] = cn;
            hv[uu] = so * ftanh(cn);
        }
        creg = make_float2(cc[0], cc[1]);
        coh_store2(houtSlot + (u0 >> 2) * 256 + b * 4 + (u0 & 3),
                   make_float2(hv[0], hv[1]));
        asm volatile("s_waitcnt vmcnt(0)" ::: "memory");  // drain both h-writer waves
    }
    __syncthreads();   // flag post (tid0) ordered after both waves' drains
}

// ---- folded prep: one wcomb row (Wh/Wc/b' fusion), hidden in enc idle ----
// j = tid (coalesced Wo column reads); Wih row uniform (s_load broadcast).
__device__ __forceinline__ void wcomb_row(
    int r, int tid,
    const float* __restrict__ WihD, const float* __restrict__ WhhD,
    const float* __restrict__ Wo,   const float* __restrict__ bd,
    const float* __restrict__ bo,
    float* __restrict__ Wh, float* __restrict__ Wc, float* __restrict__ bprime)
{
    for (int j = tid; j < 576; j += 512) {
        float acc = 0.f;
        for (int f = 0; f < 256; ++f)
            acc = fmaf(WihD[r * 256 + f], Wo[f * 576 + j], acc);
        if (j < 512) Wh[(size_t)r * 512 + j] = acc + WhhD[(size_t)r * 512 + j];
        else         Wc[(size_t)r * 64 + (j - 512)] = acc;
    }
    if (tid == 0) {
        float s = bd[r];
        for (int f = 0; f < 256; ++f)
            s = fmaf(WihD[r * 256 + f], bo[f], s);
        bprime[r] = s;
    }
}

// ---- folded prep: one g0 row, partials in the dead gsum LDS region -------
// Leading sync: finish(t)'s gsum readers (wave0 tid<64) must complete
// before other waves overwrite the region. Trailing hazard covered by
// finish(t+1)'s first barrier waiting on wave0's reduce.
__device__ __forceinline__ void g0_row(
    int r, int tid, int w, int lane,
    const float4* __restrict__ xQlast, const float* __restrict__ WihD,
    const float* __restrict__ bd, float* __restrict__ g0, float* smem)
{
    const float4* Wih4 = (const float4*)WihD;
    float acc = 0.f;
    #pragma unroll
    for (int j = 0; j < 8; ++j) {
        int q = w * 8 + j;
        float4 a  = xQlast[q * 64 + lane];
        float4 wv = Wih4[(size_t)r * 64 + q];
        acc = fmaf(a.x, wv.x, acc); acc = fmaf(a.y, wv.y, acc);
        acc = fmaf(a.z, wv.z, acc); acc = fmaf(a.w, wv.w, acc);
    }
    float* scratch = smem + 4096;     // gsum region (dead between steps)
    __syncthreads();
    scratch[w * 64 + lane] = acc;
    __syncthreads();
    if (tid < 64) {
        float s = bd[r];
        #pragma unroll
        for (int ww = 0; ww < 8; ++ww) s += scratch[ww * 64 + tid];
        g0[(size_t)r * 64 + tid] = s;
    }
}

// ---- persistent encoder: R19 dataflow + folded decoder-prep --------------
// flagsR: 8 replicas x 256 words. Consumer polls replica (bi&7).
// Steps t=0..7: wcomb row 8bi+t. Steps t=8..15: g0 row 8bi+(t-8). Both
// placed AFTER post (critical h-chain untouched; work fills spin windows).
__global__ __launch_bounds__(512, 2) void k_enc_persistent(
    const float4* __restrict__ xQ, float* __restrict__ encH,
    float* __restrict__ cT,
    const float* __restrict__ Wih, const float* __restrict__ Whh,
    const float* __restrict__ bias, unsigned* flagsR,
    const float* __restrict__ WihD, const float* __restrict__ WhhD,
    const float* __restrict__ Wo,   const float* __restrict__ bd,
    const float* __restrict__ bo,
    float* __restrict__ Wh, float* __restrict__ Wc,
    float* __restrict__ bprime, float* __restrict__ g0)
{
    __shared__ float smem[4608];
    int tid = threadIdx.x;
    int lane = tid & 63;
    int w = __builtin_amdgcn_readfirstlane(tid >> 6);
    int bi = blockIdx.x;
    int u0 = bi * 2;
    const unsigned* myFlags = flagsR + (bi & 7) * 256;   // my poll replica
    const float4* Wih4 = (const float4*)Wih;
    const float4* Whh4 = (const float4*)Whh;
    const float4* xQlast = xQ + (size_t)511 * 4096;
    float2 creg = make_float2(0.f, 0.f);
    if (tid < 64) { creg.x = cT[u0 * 64 + tid]; creg.y = cT[(u0 + 1) * 64 + tid]; }
    float acc[8];
    #pragma unroll
    for (int r = 0; r < 8; ++r) acc[r] = 0.f;
    accum_seg_pf<8>(acc, xQ, w * 8, Wih4, 64, u0, lane);       // x-part t=0
    for (int t = 0; t < 512; ++t) {
        wait_group(myFlags, w * 32, 31, (unsigned)t);           // my producers
        accum_seg_pf<16>(acc, (const float4*)(encH + (size_t)t * 32768),
                         w * 16, Whh4, 128, u0, lane);
        lstm_finish_vec(u0, tid, w, acc, creg, bias,
                        encH + (size_t)(t + 1) * 32768, smem);
        post_flag_rep(flagsR, 256, bi, (unsigned)(t + 1));
        // folded decoder-prep in the spin window (after post: chain safe)
        if (t < 8)
            wcomb_row(bi * 8 + t, tid, WihD, WhhD, Wo, bd, bo, Wh, Wc, bprime);
        else if (t < 16)
            g0_row(bi * 8 + (t - 8), tid, w, lane, xQlast, WihD, bd, g0, smem);
        #pragma unroll
        for (int r = 0; r < 8; ++r) acc[r] = 0.f;
        if (t + 1 < 512)   // x-part t+1 overlaps others' tail; stride 4096 f4
            accum_seg_pf<8>(acc, xQ + (size_t)(t + 1) * 4096, w * 8, Wih4, 64, u0, lane);
    }
    if (tid < 64) { cT[u0 * 64 + tid] = creg.x; cT[(u0 + 1) * 64 + tid] = creg.y; }
}

// ---- enc_proj + enc_attn (ba folded), round-5 form -----------------------
__global__ __launch_bounds__(256) void k_proj_attn(
    const float* __restrict__ encH,  const float* __restrict__ We_pT,
    const float* __restrict__ be_p,  const float* __restrict__ WaeT,
    const float* __restrict__ ba,
    float* __restrict__ encProj, float* __restrict__ attnPre)
{
    int lane = threadIdx.x & 63;
    int w    = __builtin_amdgcn_readfirstlane((int)threadIdx.x >> 6);
    int wid  = blockIdx.x * 4 + w;
    int b    = wid >> 6;
    int soct = wid & 63;
    float acc[8];
    float bep = be_p[lane];
    #pragma unroll
    for (int j = 0; j < 8; ++j) acc[j] = bep;
    #pragma unroll 2
    for (int q = 0; q < 128; ++q) {
        float w0 = We_pT[(4*q+0) * 64 + lane];
        float w1 = We_pT[(4*q+1) * 64 + lane];
        float w2 = We_pT[(4*q+2) * 64 + lane];
        float w3 = We_pT[(4*q+3) * 64 + lane];
        #pragma unroll
        for (int j = 0; j < 8; ++j) {
            const float4* hb4 = (const float4*)(encH + (size_t)(soct*8 + j + 1) * 32768);
            float4 hv = hb4[q * 64 + b];
            acc[j] = fmaf(hv.x, w0, acc[j]); acc[j] = fmaf(hv.y, w1, acc[j]);
            acc[j] = fmaf(hv.z, w2, acc[j]); acc[j] = fmaf(hv.w, w3, acc[j]);
        }
    }
    #pragma unroll
    for (int j = 0; j < 8; ++j)
        encProj[((size_t)b * 512 + soct * 8 + j) * 64 + lane] = acc[j];
    #pragma unroll
    for (int j = 0; j < 8; ++j) {
        float aa = ba[lane];
        for (int h2 = 0; h2 < 64; ++h2)
            aa = fmaf(__shfl(acc[j], h2), WaeT[h2 * 64 + lane], aa);
        attnPre[((size_t)b * 512 + soct * 8 + j) * 64 + lane] = aa;
    }
}

// ---- attnPre [b][s][h] -> attnPreT [b][h][s] (tile transpose) ------------
__global__ __launch_bounds__(256) void k_attn_transpose(
    const float* __restrict__ attnPre, float* __restrict__ attnPreT)
{
    __shared__ float tile[64][65];
    int b  = blockIdx.x >> 3;        // 0..63
    int s0 = (blockIdx.x & 7) * 64;  // 0..448
    int lane = threadIdx.x & 63;
    int r0   = threadIdx.x >> 6;
    for (int r = r0; r < 64; r += 4)
        tile[r][lane] = attnPre[(size_t)b * 32768 + (size_t)(s0 + r) * 64 + lane];
    __syncthreads();
    for (int r = r0; r < 64; r += 4)
        attnPreT[(size_t)b * 32768 + (size_t)r * 512 + s0 + lane] = tile[lane][r];
}

// ---- attention HALF for batch b (LDS-resident ap/ep slices) --------------
__device__ __forceinline__ void attention_half(
    int b, int tid, int w, int lane,
    const float* __restrict__ hcur,     // quad-packed h (full)
    const float* __restrict__ Wh_pT, const float* __restrict__ bh_p,
    const float* __restrict__ WahT,  const float* __restrict__ v,
    const float* __restrict__ apL,      // LDS [64][256]
    const float* __restrict__ epL,      // LDS [256][64]
    float* __restrict__ ctxsumOut,      // quad-packed (4096)
    float* __restrict__ mSOut,          // [0..63]=m, [64..127]=S per b
    float* smem)
{
    float* hq  = smem;          // 64
    float* hWa = smem + 64;     // 64
    float* sc  = smem + 128;    // 256
    float* part = smem + 384;   // 512
    float* red  = smem + 896;   // 16
    {
        const float4* h4 = (const float4*)hcur;
        float4 hv[16];
        #pragma unroll
        for (int j = 0; j < 16; ++j)
            hv[j] = h4[(w * 16 + j) * 64 + b];
        float p = 0.f;
        #pragma unroll
        for (int j = 0; j < 16; ++j) {
            int q = w * 16 + j;
            p = fmaf(hv[j].x, Wh_pT[(4*q+0) * 64 + lane], p);
            p = fmaf(hv[j].y, Wh_pT[(4*q+1) * 64 + lane], p);
            p = fmaf(hv[j].z, Wh_pT[(4*q+2) * 64 + lane], p);
            p = fmaf(hv[j].w, Wh_pT[(4*q+3) * 64 + lane], p);
        }
        part[w * 64 + lane] = p;
    }
    __syncthreads();
    if (tid < 64) {
        float s = bh_p[tid];
        #pragma unroll
        for (int ww = 0; ww < 8; ++ww) s += part[ww * 64 + tid];
        hq[tid] = s;
    }
    __syncthreads();
    if (tid < 64) {
        float s = 0.f;
        for (int j = 0; j < 64; ++j)
            s = fmaf(hq[j], WahT[j * 64 + tid], s);
        hWa[tid] = s;
    }
    __syncthreads();
    {
        int sp  = tid & 255;
        int hh0 = (tid >> 8) * 32;
        float acc = 0.f;
        for (int j = 0; j < 32; ++j) {
            int h = hh0 + j;
            float e = ftanh(hWa[h] + apL[h * 256 + sp]);
            acc = fmaf(v[h], e, acc);
        }
        part[tid] = acc;
    }
    __syncthreads();
    if (tid < 256)
        sc[tid] = part[tid] + part[256 + tid];
    __syncthreads();
    if (tid < 256) {
        float x = sc[tid];
        float m = x;
        #pragma unroll
        for (int off = 32; off > 0; off >>= 1)
            m = fmaxf(m, __shfl_xor(m, off));
        if (lane == 0) red[w] = m;
    }
    __syncthreads();
    if (tid == 0)
        red[8] = fmaxf(fmaxf(red[0], red[1]), fmaxf(red[2], red[3]));
    __syncthreads();
    float M = red[8];
    if (tid < 256) {
        float e = __expf(sc[tid] - M);
        sc[tid] = e;
        float s = e;
        #pragma unroll
        for (int off = 32; off > 0; off >>= 1)
            s += __shfl_xor(s, off);
        if (lane == 0) red[w] = s;
    }
    __syncthreads();
    if (tid == 0)
        red[9] = ((red[0] + red[1]) + (red[2] + red[3]));
    __syncthreads();
    {
        float a = 0.f;
        for (int i = 0; i < 32; ++i) {
            int sp2 = w * 32 + i;
            a = fmaf(sc[sp2], epL[sp2 * 64 + lane], a);
        }
        part[w * 64 + lane] = a;
    }
    __syncthreads();
    if (tid < 64) {
        float s = 0.f;
        #pragma unroll
        for (int ww = 0; ww < 8; ++ww) s += part[ww * 64 + tid];
        coh_store(&ctxsumOut[(tid >> 2) * 256 + b * 4 + (tid & 3)], s);
    }
    if (tid == 0) {
        coh_store(&mSOut[b], M);
        coh_store(&mSOut[64 + b], red[9]);
    }
    __syncthreads();
}

// ---- combined ctx quads for a wave (lane = b) ----------------------------
__device__ __forceinline__ void load_ctx_quads(
    int t, int w, int lane,
    const float* __restrict__ ctxsumH, const float* __restrict__ mSbuf,
    float4& c0, float4& c1)
{
    const float* mS = mSbuf + (size_t)(t - 1) * 256;
    float m0 = mS[lane],       S0 = mS[64 + lane];
    float m1 = mS[128 + lane], S1 = mS[192 + lane];
    float M  = fmaxf(m0, m1);
    float e0 = __expf(m0 - M), e1 = __expf(m1 - M);
    float inv = 1.0f / (e0 * S0 + e1 * S1);
    e0 *= inv; e1 *= inv;
    const float4* a0 = (const float4*)(ctxsumH + (size_t)(t - 1) * 8192);
    const float4* a1 = (const float4*)(ctxsumH + (size_t)(t - 1) * 8192 + 4096);
    float4 x0 = a0[(w * 2 + 0) * 64 + lane];
    float4 y0 = a1[(w * 2 + 0) * 64 + lane];
    float4 x1 = a0[(w * 2 + 1) * 64 + lane];
    float4 y1 = a1[(w * 2 + 1) * 64 + lane];
    c0 = make_float4(e0 * x0.x + e1 * y0.x, e0 * x0.y + e1 * y0.y,
                     e0 * x0.z + e1 * y0.z, e0 * x0.w + e1 * y0.w);
    c1 = make_float4(e0 * x1.x + e1 * y1.x, e0 * x1.y + e1 * y1.y,
                     e0 * x1.z + e1 * y1.z, e0 * x1.w + e1 * y1.w);
}

// ---- persistent decoder: 128 attn-half blocks + 128 LSTM blocks ----------
// Dynamic LDS layout (149504 B): scratch@0 (attn 4608 / lstm part 8192 —
// DISJOINT block roles) | apL@4608 (16384) | epL@20992 (16384).
// attnFlagsR/lstmFlagsR: 8 replicas x 128 words each (R19 contention win).
extern __shared__ float dynsmem[];
__global__ __launch_bounds__(512) void k_dec_persistent(
    const float* __restrict__ encHend,
    float* __restrict__ dechH,            // [96][quad 32768]
    float* __restrict__ cT,
    const float* __restrict__ Whh,        // t=0 h-part
    const float* __restrict__ Wh,         // t>=1 fused h-part
    const float* __restrict__ Wc,         // ctx part
    const float* __restrict__ g0, const float* __restrict__ bprime,
    const float* __restrict__ Wh_pT, const float* __restrict__ bh_p,
    const float* __restrict__ WahT,  const float* __restrict__ v,
    const float* __restrict__ attnPreT, const float* __restrict__ encProj,
    float* __restrict__ ctxsumH,          // [96][2][4096]
    float* __restrict__ mSbuf,            // [96][256]
    unsigned* attnFlagsR, unsigned* lstmFlagsR)
{
    float* smem = dynsmem;                // attn scratch 4608 / lstm part 8192
    float* apL  = dynsmem + 4608;         // 16384: [h][s']   (attn only)
    float* epL  = apL + 16384;            // 16384: [s'][h2]  (attn only)
    int tid = threadIdx.x;
    int lane = tid & 63;
    int w = __builtin_amdgcn_readfirstlane(tid >> 6);
    int bi = blockIdx.x;
    int rep = bi & 7;
    const unsigned* myLstmF = lstmFlagsR + rep * 128;
    const unsigned* myAttnF = attnFlagsR + rep * 128;
    if (bi < 128) {
        int b = bi & 63, half = bi >> 6;
        {
            const float4* src = (const float4*)(attnPreT + (size_t)b * 32768 + half * 256);
            float4* dst = (float4*)apL;
            for (int i = tid; i < 4096; i += 512) {
                int h = i >> 6, qc = i & 63;
                dst[i] = src[(size_t)h * 128 + qc];
            }
        }
        {
            const float4* src = (const float4*)(encProj + ((size_t)b * 512 + half * 256) * 64);
            float4* dst = (float4*)epL;
            for (int i = tid; i < 4096; i += 512)
                dst[i] = src[i];
        }
        __syncthreads();
        for (int t = 0; t < 96; ++t) {
            if (t) wait_group(myLstmF, (w & 3) * 32, 31, (unsigned)t);
            const float* hc = t ? dechH + (size_t)(t - 1) * 32768 : encHend;
            attention_half(b, tid, w, lane, hc, Wh_pT, bh_p, WahT, v,
                           apL, epL,
                           ctxsumH + (size_t)t * 8192 + half * 4096,
                           mSbuf + (size_t)t * 256 + half * 128, smem);
            post_flag_rep(attnFlagsR, 128, bi, (unsigned)(t + 1));
        }
    } else {
        int u0A = (bi - 128) * 2;
        int u0B = u0A + 256;
        const float4* Whh4 = (const float4*)Whh;
        const float4* Wh4  = (const float4*)Wh;
        const float4* Wc4  = (const float4*)Wc;
        // c-state: wave0 threads hold pair A, wave1 threads hold pair B.
        float2 creg = make_float2(0.f, 0.f);
        if (tid < 64) {
            creg.x = cT[u0A * 64 + tid]; creg.y = cT[(u0A + 1) * 64 + tid];
        } else if (tid < 128) {
            creg.x = cT[u0B * 64 + (tid - 64)];
            creg.y = cT[(u0B + 1) * 64 + (tid - 64)];
        }
        for (int t = 0; t < 96; ++t) {
            if (t) wait_lstm_inputs(myAttnF, myLstmF, w, (unsigned)t);
            const float* hc = t ? dechH + (size_t)(t - 1) * 32768 : encHend;
            float* hn = dechH + (size_t)t * 32768;
            float accA[8], accB[8];
            #pragma unroll
            for (int r = 0; r < 8; ++r) { accA[r] = 0.f; accB[r] = 0.f; }
            if (t == 0) {
                accum_seg_pf2<16>(accA, accB, (const float4*)hc, w * 16,
                                  Whh4, 128, u0A, u0B, lane);
                lstm_finish2<true>(u0A, u0B, tid, w, accA, accB, creg,
                                   nullptr, g0, hn, smem);
            } else {
                float4 cq0, cq1;
                load_ctx_quads(t, w, lane, ctxsumH, mSbuf, cq0, cq1);
                accum_seg_pf2<16>(accA, accB, (const float4*)hc, w * 16,
                                  Wh4, 128, u0A, u0B, lane);
                accum_ctx_reg(accA, cq0, cq1, Wc4, u0A, w);
                accum_ctx_reg(accB, cq0, cq1, Wc4, u0B, w);
                lstm_finish2<false>(u0A, u0B, tid, w, accA, accB, creg,
                                    bprime, nullptr, hn, smem);
            }
            post_flag_rep(lstmFlagsR, 128, bi - 128, (unsigned)(t + 1));
        }
    }
}

// ---- post-pass: dout[b][tau] = Wo[255].[h^{(tau+1)}; ctx_tau] + bo[255] --
__global__ __launch_bounds__(256) void k_dout(
    const float* __restrict__ dechH,
    const float* __restrict__ ctxsumH, const float* __restrict__ mSbuf,
    const float* __restrict__ Wo, const float* __restrict__ bo,
    float* __restrict__ dout)
{
    __shared__ float part[256];
    int tau = blockIdx.x;            // 0..95
    int tid = threadIdx.x;
    int lane = tid & 63;             // = b
    int w = tid >> 6;                // 0..3
    const float* hq = dechH + (size_t)tau * 32768;
    const float* wrow = Wo + 255 * 576;
    float acc = 0.f;
    for (int i = w * 128; i < w * 128 + 128; ++i)
        acc = fmaf(wrow[i], hq[(i >> 2) * 256 + lane * 4 + (i & 3)], acc);
    part[w * 64 + lane] = acc;
    __syncthreads();
    if (tid < 64) {
        int b = tid;
        const float* mS = mSbuf + (size_t)tau * 256;
        float m0 = mS[b],       S0 = mS[64 + b];
        float m1 = mS[128 + b], S1 = mS[192 + b];
        float M  = fmaxf(m0, m1);
        float e0 = __expf(m0 - M), e1 = __expf(m1 - M);
        float inv = 1.0f / (e0 * S0 + e1 * S1);
        e0 *= inv; e1 *= inv;
        const float* cs0 = ctxsumH + (size_t)tau * 8192;
        const float* cs1 = cs0 + 4096;
        float a2 = bo[255];
        for (int h2 = 0; h2 < 64; ++h2) {
            int idx = (h2 >> 2) * 256 + b * 4 + (h2 & 3);
            a2 = fmaf(wrow[512 + h2], e0 * cs0[idx] + e1 * cs1[idx], a2);
        }
        float s = a2 + part[b] + part[64 + b] + part[128 + b] + part[192 + b];
        dout[b * 96 + tau] = s;
    }
}

} // namespace

extern "C" void kernel_launch(void* const* d_in, const int* in_sizes, int n_in,
                              void* d_out, int out_size, void* d_ws, size_t ws_size,
                              hipStream_t stream)
{
    (void)in_sizes; (void)n_in; (void)out_size; (void)ws_size;
    const float* input_seq = (const float*)d_in[0];
    const float* h0     = (const float*)d_in[1];
    const float* c0     = (const float*)d_in[2];
    const float* W_ih_e = (const float*)d_in[3];
    const float* W_hh_e = (const float*)d_in[4];
    const float* b_e    = (const float*)d_in[5];
    const float* W_ih_d = (const float*)d_in[6];
    const float* W_hh_d = (const float*)d_in[7];
    const float* b_d    = (const float*)d_in[8];
    const float* We_p   = (const float*)d_in[9];
    const float* be_p   = (const float*)d_in[10];
    const float* Wh_p   = (const float*)d_in[11];
    const float* bh_p   = (const float*)d_in[12];
    const float* Wa     = (const float*)d_in[13];
    const float* ba     = (const float*)d_in[14];
    const float* v      = (const float*)d_in[15];
    const float* Wo     = (const float*)d_in[16];
    const float* bo     = (const float*)d_in[17];
    float* out = (float*)d_out;

    // Flag replicas: enc 8x256 | attn 8x128 | lstm 8x128 = 4096 words (16KB).
    unsigned* encFlagsR  = (unsigned*)d_ws;     // [8][256]
    unsigned* attnFlagsR = encFlagsR + 2048;    // [8][128]
    unsigned* lstmFlagsR = attnFlagsR + 1024;   // [8][128]
    float* ws       = (float*)d_ws + 4096;      // 16KB offset
    float* xT       = ws;                       // 8388608 (dead after enc/g0)
    float* encH     = xT + 8388608;             // 513*32768 = 16809984
    float* cT       = encH + 16809984;          // 32768
    float* We_pT    = cT + 32768;               // 32768
    float* Wh_pT    = We_pT + 32768;            // 32768
    float* WahT     = Wh_pT + 32768;            // 4096
    float* WaeT     = WahT + 4096;              // 4096
    float* encProj  = WaeT + 4096;              // 2097152
    float* attnPre  = encProj + 2097152;        // 2097152
    float* dechH    = attnPre + 2097152;        // 96*32768 = 3145728
    float* ctxsumH  = dechH + 3145728;          // 96*2*4096 = 786432
    float* mSbuf    = ctxsumH + 786432;         // 96*256 = 24576
    float* Wh       = mSbuf + 24576;            // 2048*512 = 1048576
    float* Wc       = Wh + 1048576;             // 2048*64 = 131072
    float* bprime   = Wc + 131072;              // 2048
    float* g0       = bprime + 2048;            // 2048*64 = 131072
    float* attnPreT = xT;                       // aliases dead xT region (2M)

    (void)hipFuncSetAttribute((const void*)k_dec_persistent,
                              hipFuncAttributeMaxDynamicSharedMemorySize, 149504);

    (void)hipMemsetAsync(d_ws, 0, 16384, stream); // zero all flag replicas
    k_transpose_input<<<2048, 256, 0, stream>>>(input_seq, (float4*)xT);
    k_prep<<<544, 256, 0, stream>>>(We_p, Wh_p, h0, c0, Wa,
                                    We_pT, Wh_pT, encH, cT, WahT, WaeT);
    // k_prep_wcomb / k_prep_g0 folded into k_enc_persistent idle windows.
    k_enc_persistent<<<256, 512, 0, stream>>>((const float4*)xT, encH, cT,
                                              W_ih_e, W_hh_e, b_e, encFlagsR,
                                              W_ih_d, W_hh_d, Wo, b_d, bo,
                                              Wh, Wc, bprime, g0);
    k_proj_attn<<<1024, 256, 0, stream>>>(encH, We_pT, be_p, WaeT, ba,
                                          encProj, attnPre);
    k_attn_transpose<<<512, 256, 0, stream>>>(attnPre, attnPreT);
    k_dec_persistent<<<256, 512, 149504, stream>>>(encH + (size_t)512 * 32768,
                                                   dechH, cT,
                                                   W_hh_d, Wh, Wc, g0, bprime,
                                                   Wh_pT, bh_p, WahT, v,
                                                   attnPreT, encProj,
                                                   ctxsumH, mSbuf,
                                                   attnFlagsR, lstmFlagsR);
    k_dout<<<96, 256, 0, stream>>>(dechH, ctxsumH, mSbuf, Wo, bo, out);
}

// Round 12
// 5213.767 us; speedup vs baseline: 1.7954x; 1.0406x over previous
//
#include <hip/hip_runtime.h>

// Seq2seq LSTM + attention — persistent kernels, ROUND-22: revert to R19.
//
// FINAL LEDGER:
//  R12 dataflow sync (per-wave producer flags)        5735  WIN  (-1.8ms)
//  R13 16-wave encoder                                REGRESS (serial chain)
//  R14 nontemporal act loads                          REGRESS (L2 retention)
//  R15/16 decoder A/B merge + LDS-size fix            5574  WIN
//  R17 vector weight path                             REGRESS 2x (s_load wins)
//  R19 flag replication (8 replicas, poll bi&7)       5239  WIN (dec contention)
//  R20 data-as-flag encoder                           REGRESS 2.3x (uncoalesced)
//  R21 prep-fold into enc idle windows                REGRESS (+187us: VGPR/cache
//      pressure in the persistent loop taxes all 512 steps; prep was ~free)
//
// Conclusions baked into this code:
//  - Sync topology: per-wave producer-group flags, 8x replicated, poll
//    replica (bi&7). Bulk data stays on the coalesced cached path; one
//    drain + flag store per producer step.
//  - Uniform weights via SGPR-addressed s_load K$ broadcast (do not
//    vectorize).
//  - Both persistent kernels at their measured topology floor
//    (~6.3us/enc-step, ~9us/dec-step); remaining serial prep ~free.
// This file is byte-equivalent to the verified R19 (5239us, absmax 0.0).

namespace {

__device__ __forceinline__ float fsigmoid(float x) {
    return 1.0f / (1.0f + __expf(-x));
}
__device__ __forceinline__ float ftanh(float x) {
    float e = __expf(2.0f * x);
    return 1.0f - 2.0f / (e + 1.0f);
}

__device__ __forceinline__ void coh_store(float* p, float v) {
    __hip_atomic_store(p, v, __ATOMIC_RELAXED, __HIP_MEMORY_SCOPE_AGENT);
}
__device__ __forceinline__ void coh_store2(float* p, float2 v) {
    union { float2 f; unsigned long long u; } cv; cv.f = v;
    __hip_atomic_store((unsigned long long*)p, cv.u,
                       __ATOMIC_RELAXED, __HIP_MEMORY_SCOPE_AGENT);
}

// ---- replicated dataflow flags -------------------------------------------
// 8 replicas, stride words apart. Producer: ONE vmcnt drain (proves its
// data stores reached the coherent point), then 8 replica posts — any
// replica >= val implies the data is visible. Consumer polls replica
// (its block id & 7) so pollers-per-line drop 8x.
__device__ __forceinline__ void post_flag_rep(unsigned* flags, int stride,
                                              int idx, unsigned val) {
    if (threadIdx.x == 0) {
        asm volatile("s_waitcnt vmcnt(0)" ::: "memory");
        #pragma unroll
        for (int r = 0; r < 8; ++r)
            __hip_atomic_store(&flags[r * stride + idx], val,
                               __ATOMIC_RELAXED, __HIP_MEMORY_SCOPE_AGENT);
    }
}
// wait: the whole wave polls producer flags (lane&mask -> one flag each).
// `flags` is already replica-adjusted by the caller.
__device__ __forceinline__ void wait_group(const unsigned* flags, int base,
                                           int mask, unsigned val) {
    const unsigned* f = flags + base + (threadIdx.x & mask);
    for (;;) {
        unsigned x = __hip_atomic_load(f, __ATOMIC_RELAXED, __HIP_MEMORY_SCOPE_AGENT);
        if (__all(x >= val)) break;
        __builtin_amdgcn_s_sleep(1);
    }
    asm volatile("" ::: "memory");   // no hoisting of data loads above poll
}
// dec LSTM wait: h group (32 flags) + all 128 attn flags (ctx all-to-all).
// attnF/lstmF already replica-adjusted.
__device__ __forceinline__ void wait_lstm_inputs(const unsigned* attnF,
                                                 const unsigned* lstmF,
                                                 int w, unsigned val) {
    int lane = threadIdx.x & 63;
    const unsigned* fa = attnF + lane * 2;
    const unsigned* fl = lstmF + (w & 3) * 32 + (lane & 31);
    for (;;) {
        unsigned a = __hip_atomic_load(fa + 0, __ATOMIC_RELAXED, __HIP_MEMORY_SCOPE_AGENT);
        unsigned b = __hip_atomic_load(fa + 1, __ATOMIC_RELAXED, __HIP_MEMORY_SCOPE_AGENT);
        unsigned c = __hip_atomic_load(fl,     __ATOMIC_RELAXED, __HIP_MEMORY_SCOPE_AGENT);
        int ok = (a >= val) && (b >= val) && (c >= val);
        if (__all(ok)) break;
        __builtin_amdgcn_s_sleep(1);
    }
    asm volatile("" ::: "memory");
}

// ---- transpose input_seq (B,S,F) -> quad layout [s][f/4][b][4] -----------
__global__ __launch_bounds__(256) void k_transpose_input(
    const float* __restrict__ in, float4* __restrict__ xQ)
{
    __shared__ float tile[64][65];
    int s  = blockIdx.x >> 2;
    int f0 = (blockIdx.x & 3) * 64;
    int lane = threadIdx.x & 63;
    int r0   = threadIdx.x >> 6;
    for (int r = r0; r < 64; r += 4)
        tile[r][lane] = in[(size_t)r * (512 * 256) + s * 256 + f0 + lane];
    __syncthreads();
    for (int q = r0; q < 16; q += 4) {
        float4 vv = make_float4(tile[lane][4*q], tile[lane][4*q+1],
                                tile[lane][4*q+2], tile[lane][4*q+3]);
        xQ[((size_t)s * 64 + (f0 >> 2) + q) * 64 + lane] = vv;
    }
}

// ---- small weight/state transposes; encH slot0 quad-packed ---------------
__global__ __launch_bounds__(256) void k_prep(
    const float* __restrict__ We_p, const float* __restrict__ Wh_p,
    const float* __restrict__ h0,   const float* __restrict__ c0,
    const float* __restrict__ Wa,
    float* __restrict__ We_pT, float* __restrict__ Wh_pT,
    float* __restrict__ encH0, float* __restrict__ cT,
    float* __restrict__ WahT,  float* __restrict__ WaeT)
{
    int idx = blockIdx.x * blockDim.x + threadIdx.x;
    const int total = 32768 * 4 + 4096 * 2;
    for (; idx < total; idx += gridDim.x * blockDim.x) {
        if (idx < 32768) {
            int u = idx >> 6, h = idx & 63;
            We_pT[idx] = We_p[h * 512 + u];
        } else if (idx < 65536) {
            int i2 = idx - 32768; int k = i2 >> 6, i = i2 & 63;
            Wh_pT[i2] = Wh_p[i * 512 + k];
        } else if (idx < 98304) {
            int i2 = idx - 65536; int u = i2 >> 6, b = i2 & 63;
            encH0[(u >> 2) * 256 + b * 4 + (u & 3)] = h0[b * 512 + u];
        } else if (idx < 131072) {
            int i2 = idx - 98304; int u = i2 >> 6, b = i2 & 63;
            cT[i2] = c0[b * 512 + u];
        } else if (idx < 135168) {
            int i2 = idx - 131072; int j = i2 >> 6, i = i2 & 63;
            WahT[i2] = Wa[i * 128 + j];
        } else {
            int i2 = idx - 135168; int h2 = i2 >> 6, h = i2 & 63;
            WaeT[i2] = Wa[h * 128 + 64 + h2];
        }
    }
}

// ---- W_h = Wih_d.Wo[:, :512] + Whh_d ; W_c = Wih_d.Wo[:, 512:] ; b' ------
__global__ __launch_bounds__(256) void k_prep_wcomb(
    const float* __restrict__ Wih, const float* __restrict__ Whh,
    const float* __restrict__ Wo,  const float* __restrict__ bd,
    const float* __restrict__ bo,
    float* __restrict__ Wh, float* __restrict__ Wc, float* __restrict__ bprime)
{
    int r = blockIdx.x;          // 0..2047
    for (int j = threadIdx.x; j < 576; j += 256) {
        float acc = 0.f;
        for (int f = 0; f < 256; ++f)
            acc = fmaf(Wih[r * 256 + f], Wo[f * 576 + j], acc);
        if (j < 512) Wh[(size_t)r * 512 + j] = acc + Whh[(size_t)r * 512 + j];
        else         Wc[(size_t)r * 64 + (j - 512)] = acc;
    }
    if (threadIdx.x == 0) {
        float s = bd[r];
        for (int f = 0; f < 256; ++f)
            s = fmaf(Wih[r * 256 + f], bo[f], s);
        bprime[r] = s;
    }
}

// ---- g0[r][b] = Wih_d . x_last + b_d -------------------------------------
__global__ __launch_bounds__(256) void k_prep_g0(
    const float4* __restrict__ xQlast, const float* __restrict__ Wih,
    const float* __restrict__ bd, float* __restrict__ g0)
{
    int r = blockIdx.x * 4 + ((int)threadIdx.x >> 6);
    int lane = threadIdx.x & 63;
    const float4* Wih4 = (const float4*)Wih;
    float acc = bd[r];
    for (int q = 0; q < 64; ++q) {
        float4 a  = xQlast[q * 64 + lane];
        float4 wv = Wih4[(size_t)r * 64 + q];
        acc = fmaf(a.x, wv.x, acc); acc = fmaf(a.y, wv.y, acc);
        acc = fmaf(a.z, wv.z, acc); acc = fmaf(a.w, wv.w, acc);
    }
    g0[(size_t)r * 64 + lane] = acc;
}

// ---- gate-GEMM accumulation, register-prefetched (one unit-pair) ---------
// Weight addresses SGPR-derived on purpose (R17: s_load K$ broadcast wins).
template<int NQ>
__device__ __forceinline__ void accum_seg_pf(
    float acc[8], const float4* __restrict__ actQ, int qb,
    const float4* __restrict__ W4, int wstride, int u0, int lane)
{
    float4 a[NQ];
    #pragma unroll
    for (int q = 0; q < NQ; ++q)
        a[q] = actQ[(qb + q) * 64 + lane];
    #pragma unroll
    for (int q = 0; q < NQ; ++q) {
        #pragma unroll
        for (int uu = 0; uu < 2; ++uu)
            #pragma unroll
            for (int g = 0; g < 4; ++g) {
                float4 wv = W4[(size_t)(g * 512 + u0 + uu) * wstride + (qb + q)];
                float& A = acc[uu * 4 + g];
                A = fmaf(a[q].x, wv.x, A); A = fmaf(a[q].y, wv.y, A);
                A = fmaf(a[q].z, wv.z, A); A = fmaf(a[q].w, wv.w, A);
            }
    }
}

// ---- merged two-pair accumulation: acts loaded ONCE (decoder) ------------
template<int NQ>
__device__ __forceinline__ void accum_seg_pf2(
    float accA[8], float accB[8], const float4* __restrict__ actQ, int qb,
    const float4* __restrict__ W4, int wstride, int u0A, int u0B, int lane)
{
    float4 a[NQ];
    #pragma unroll
    for (int q = 0; q < NQ; ++q)
        a[q] = actQ[(qb + q) * 64 + lane];
    #pragma unroll
    for (int q = 0; q < NQ; ++q) {
        #pragma unroll
        for (int uu = 0; uu < 2; ++uu)
            #pragma unroll
            for (int g = 0; g < 4; ++g) {
                float4 wA = W4[(size_t)(g * 512 + u0A + uu) * wstride + (qb + q)];
                float4 wB = W4[(size_t)(g * 512 + u0B + uu) * wstride + (qb + q)];
                float& A = accA[uu * 4 + g];
                float& Bv = accB[uu * 4 + g];
                A = fmaf(a[q].x, wA.x, A); A = fmaf(a[q].y, wA.y, A);
                A = fmaf(a[q].z, wA.z, A); A = fmaf(a[q].w, wA.w, A);
                Bv = fmaf(a[q].x, wB.x, Bv); Bv = fmaf(a[q].y, wB.y, Bv);
                Bv = fmaf(a[q].z, wB.z, Bv); Bv = fmaf(a[q].w, wB.w, Bv);
            }
    }
}

// ---- ctx-part accumulation from pre-combined register quads --------------
__device__ __forceinline__ void accum_ctx_reg(
    float acc[8], float4 c0, float4 c1,
    const float4* __restrict__ Wc4, int u0, int w)
{
    #pragma unroll
    for (int uu = 0; uu < 2; ++uu)
        #pragma unroll
        for (int g = 0; g < 4; ++g) {
            float4 w0 = Wc4[(size_t)(g * 512 + u0 + uu) * 16 + w * 2 + 0];
            float4 w1 = Wc4[(size_t)(g * 512 + u0 + uu) * 16 + w * 2 + 1];
            float& A = acc[uu * 4 + g];
            A = fmaf(c0.x, w0.x, A); A = fmaf(c0.y, w0.y, A);
            A = fmaf(c0.z, w0.z, A); A = fmaf(c0.w, w0.w, A);
            A = fmaf(c1.x, w1.x, A); A = fmaf(c1.y, w1.y, A);
            A = fmaf(c1.z, w1.z, A); A = fmaf(c1.w, w1.w, A);
        }
}

// ---- finish variant 1: additive = per-row vector (bias / b') — encoder ---
__device__ __forceinline__ void lstm_finish_vec(
    int u0, int tid, int w, float acc[8], float2& creg,
    const float* __restrict__ addVec, float* __restrict__ houtSlot, float* smem)
{
    int lane = tid & 63;
    float* part = smem;          // [8][8][64]
    float* gsum = smem + 4096;   // [8][64]
    #pragma unroll
    for (int r = 0; r < 8; ++r)
        part[(w * 8 + r) * 64 + lane] = acc[r];
    __syncthreads();
    {
        int b = tid & 63, r = tid >> 6;
        float s = 0.f;
        #pragma unroll
        for (int ww = 0; ww < 8; ++ww)
            s += part[(ww * 8 + r) * 64 + b];
        gsum[r * 64 + b] = s;
    }
    __syncthreads();
    if (tid < 64) {
        int b = tid;
        float cc[2] = {creg.x, creg.y};
        float hv[2];
        #pragma unroll
        for (int uu = 0; uu < 2; ++uu) {
            int u = u0 + uu;
            float gi = gsum[(uu*4+0)*64 + b] + addVec[u];
            float gf = gsum[(uu*4+1)*64 + b] + addVec[512 + u];
            float gg = gsum[(uu*4+2)*64 + b] + addVec[1024 + u];
            float go = gsum[(uu*4+3)*64 + b] + addVec[1536 + u];
            float si = fsigmoid(gi), sf = fsigmoid(gf), so = fsigmoid(go);
            float tg = ftanh(gg);
            float cn = sf * cc[uu] + si * tg;
            cc[uu] = cn;
            hv[uu] = so * ftanh(cn);
        }
        creg = make_float2(cc[0], cc[1]);
        coh_store2(houtSlot + (u0 >> 2) * 256 + b * 4 + (u0 & 3),
                   make_float2(hv[0], hv[1]));
    }
}

// ---- merged decoder finish: pair A by wave0-threads, pair B by wave1 -----
template<bool ROWADD>
__device__ __forceinline__ void lstm_finish2(
    int u0A, int u0B, int tid, int w, float accA[8], float accB[8],
    float2& creg, const float* __restrict__ addVec,
    const float* __restrict__ addRowB,
    float* __restrict__ houtSlot, float* smem)
{
    int lane = tid & 63;
    float* part = smem;                  // [8][16][64] = 8192 floats
    #pragma unroll
    for (int r = 0; r < 8; ++r)
        part[(w * 16 + r) * 64 + lane] = accA[r];
    #pragma unroll
    for (int r = 0; r < 8; ++r)
        part[(w * 16 + 8 + r) * 64 + lane] = accB[r];
    __syncthreads();
    if (tid < 128) {
        int b  = tid & 63;
        int ps = tid >> 6;               // 0 = pair A, 1 = pair B
        int u0 = ps ? u0B : u0A;
        float cc[2] = {creg.x, creg.y};
        float hv[2];
        #pragma unroll
        for (int uu = 0; uu < 2; ++uu) {
            int u = u0 + uu;
            float gate[4];
            #pragma unroll
            for (int g = 0; g < 4; ++g) {
                int row = ps * 8 + uu * 4 + g;
                float s = 0.f;
                #pragma unroll
                for (int ww = 0; ww < 8; ++ww)
                    s += part[(ww * 16 + row) * 64 + b];
                if (ROWADD) s += addRowB[(size_t)(g * 512 + u) * 64 + b];
                else        s += addVec[g * 512 + u];
                gate[g] = s;
            }
            float si = fsigmoid(gate[0]), sf = fsigmoid(gate[1]);
            float so = fsigmoid(gate[3]);
            float tg = ftanh(gate[2]);
            float cn = sf * cc[uu] + si * tg;
            cc[uu] = cn;
            hv[uu] = so * ftanh(cn);
        }
        creg = make_float2(cc[0], cc[1]);
        coh_store2(houtSlot + (u0 >> 2) * 256 + b * 4 + (u0 & 3),
                   make_float2(hv[0], hv[1]));
        asm volatile("s_waitcnt vmcnt(0)" ::: "memory");  // drain both h-writer waves
    }
    __syncthreads();   // flag post (tid0) ordered after both waves' drains
}

// ---- persistent encoder: per-wave producer-group dataflow ----------------
// flagsR: 8 replicas x 256 words. Consumer polls replica (bi&7).
__global__ __launch_bounds__(512, 2) void k_enc_persistent(
    const float4* __restrict__ xQ, float* __restrict__ encH,
    float* __restrict__ cT,
    const float* __restrict__ Wih, const float* __restrict__ Whh,
    const float* __restrict__ bias, unsigned* flagsR)
{
    __shared__ float smem[4608];
    int tid = threadIdx.x;
    int lane = tid & 63;
    int w = __builtin_amdgcn_readfirstlane(tid >> 6);
    int bi = blockIdx.x;
    int u0 = bi * 2;
    const unsigned* myFlags = flagsR + (bi & 7) * 256;   // my poll replica
    const float4* Wih4 = (const float4*)Wih;
    const float4* Whh4 = (const float4*)Whh;
    float2 creg = make_float2(0.f, 0.f);
    if (tid < 64) { creg.x = cT[u0 * 64 + tid]; creg.y = cT[(u0 + 1) * 64 + tid]; }
    float acc[8];
    #pragma unroll
    for (int r = 0; r < 8; ++r) acc[r] = 0.f;
    accum_seg_pf<8>(acc, xQ, w * 8, Wih4, 64, u0, lane);       // x-part t=0
    for (int t = 0; t < 512; ++t) {
        wait_group(myFlags, w * 32, 31, (unsigned)t);           // my producers
        accum_seg_pf<16>(acc, (const float4*)(encH + (size_t)t * 32768),
                         w * 16, Whh4, 128, u0, lane);
        lstm_finish_vec(u0, tid, w, acc, creg, bias,
                        encH + (size_t)(t + 1) * 32768, smem);
        post_flag_rep(flagsR, 256, bi, (unsigned)(t + 1));
        #pragma unroll
        for (int r = 0; r < 8; ++r) acc[r] = 0.f;
        if (t + 1 < 512)   // x-part t+1 overlaps others' tail; stride 4096 f4
            accum_seg_pf<8>(acc, xQ + (size_t)(t + 1) * 4096, w * 8, Wih4, 64, u0, lane);
    }
    if (tid < 64) { cT[u0 * 64 + tid] = creg.x; cT[(u0 + 1) * 64 + tid] = creg.y; }
}

// ---- enc_proj + enc_attn (ba folded), round-5 form -----------------------
__global__ __launch_bounds__(256) void k_proj_attn(
    const float* __restrict__ encH,  const float* __restrict__ We_pT,
    const float* __restrict__ be_p,  const float* __restrict__ WaeT,
    const float* __restrict__ ba,
    float* __restrict__ encProj, float* __restrict__ attnPre)
{
    int lane = threadIdx.x & 63;
    int w    = __builtin_amdgcn_readfirstlane((int)threadIdx.x >> 6);
    int wid  = blockIdx.x * 4 + w;
    int b    = wid >> 6;
    int soct = wid & 63;
    float acc[8];
    float bep = be_p[lane];
    #pragma unroll
    for (int j = 0; j < 8; ++j) acc[j] = bep;
    #pragma unroll 2
    for (int q = 0; q < 128; ++q) {
        float w0 = We_pT[(4*q+0) * 64 + lane];
        float w1 = We_pT[(4*q+1) * 64 + lane];
        float w2 = We_pT[(4*q+2) * 64 + lane];
        float w3 = We_pT[(4*q+3) * 64 + lane];
        #pragma unroll
        for (int j = 0; j < 8; ++j) {
            const float4* hb4 = (const float4*)(encH + (size_t)(soct*8 + j + 1) * 32768);
            float4 hv = hb4[q * 64 + b];
            acc[j] = fmaf(hv.x, w0, acc[j]); acc[j] = fmaf(hv.y, w1, acc[j]);
            acc[j] = fmaf(hv.z, w2, acc[j]); acc[j] = fmaf(hv.w, w3, acc[j]);
        }
    }
    #pragma unroll
    for (int j = 0; j < 8; ++j)
        encProj[((size_t)b * 512 + soct * 8 + j) * 64 + lane] = acc[j];
    #pragma unroll
    for (int j = 0; j < 8; ++j) {
        float aa = ba[lane];
        for (int h2 = 0; h2 < 64; ++h2)
            aa = fmaf(__shfl(acc[j], h2), WaeT[h2 * 64 + lane], aa);
        attnPre[((size_t)b * 512 + soct * 8 + j) * 64 + lane] = aa;
    }
}

// ---- attnPre [b][s][h] -> attnPreT [b][h][s] (tile transpose) ------------
__global__ __launch_bounds__(256) void k_attn_transpose(
    const float* __restrict__ attnPre, float* __restrict__ attnPreT)
{
    __shared__ float tile[64][65];
    int b  = blockIdx.x >> 3;        // 0..63
    int s0 = (blockIdx.x & 7) * 64;  // 0..448
    int lane = threadIdx.x & 63;
    int r0   = threadIdx.x >> 6;
    for (int r = r0; r < 64; r += 4)
        tile[r][lane] = attnPre[(size_t)b * 32768 + (size_t)(s0 + r) * 64 + lane];
    __syncthreads();
    for (int r = r0; r < 64; r += 4)
        attnPreT[(size_t)b * 32768 + (size_t)r * 512 + s0 + lane] = tile[lane][r];
}

// ---- attention HALF for batch b (LDS-resident ap/ep slices) --------------
__device__ __forceinline__ void attention_half(
    int b, int tid, int w, int lane,
    const float* __restrict__ hcur,     // quad-packed h (full)
    const float* __restrict__ Wh_pT, const float* __restrict__ bh_p,
    const float* __restrict__ WahT,  const float* __restrict__ v,
    const float* __restrict__ apL,      // LDS [64][256]
    const float* __restrict__ epL,      // LDS [256][64]
    float* __restrict__ ctxsumOut,      // quad-packed (4096)
    float* __restrict__ mSOut,          // [0..63]=m, [64..127]=S per b
    float* smem)
{
    float* hq  = smem;          // 64
    float* hWa = smem + 64;     // 64
    float* sc  = smem + 128;    // 256
    float* part = smem + 384;   // 512
    float* red  = smem + 896;   // 16
    {
        const float4* h4 = (const float4*)hcur;
        float4 hv[16];
        #pragma unroll
        for (int j = 0; j < 16; ++j)
            hv[j] = h4[(w * 16 + j) * 64 + b];
        float p = 0.f;
        #pragma unroll
        for (int j = 0; j < 16; ++j) {
            int q = w * 16 + j;
            p = fmaf(hv[j].x, Wh_pT[(4*q+0) * 64 + lane], p);
            p = fmaf(hv[j].y, Wh_pT[(4*q+1) * 64 + lane], p);
            p = fmaf(hv[j].z, Wh_pT[(4*q+2) * 64 + lane], p);
            p = fmaf(hv[j].w, Wh_pT[(4*q+3) * 64 + lane], p);
        }
        part[w * 64 + lane] = p;
    }
    __syncthreads();
    if (tid < 64) {
        float s = bh_p[tid];
        #pragma unroll
        for (int ww = 0; ww < 8; ++ww) s += part[ww * 64 + tid];
        hq[tid] = s;
    }
    __syncthreads();
    if (tid < 64) {
        float s = 0.f;
        for (int j = 0; j < 64; ++j)
            s = fmaf(hq[j], WahT[j * 64 + tid], s);
        hWa[tid] = s;
    }
    __syncthreads();
    {
        int sp  = tid & 255;
        int hh0 = (tid >> 8) * 32;
        float acc = 0.f;
        for (int j = 0; j < 32; ++j) {
            int h = hh0 + j;
            float e = ftanh(hWa[h] + apL[h * 256 + sp]);
            acc = fmaf(v[h], e, acc);
        }
        part[tid] = acc;
    }
    __syncthreads();
    if (tid < 256)
        sc[tid] = part[tid] + part[256 + tid];
    __syncthreads();
    if (tid < 256) {
        float x = sc[tid];
        float m = x;
        #pragma unroll
        for (int off = 32; off > 0; off >>= 1)
            m = fmaxf(m, __shfl_xor(m, off));
        if (lane == 0) red[w] = m;
    }
    __syncthreads();
    if (tid == 0)
        red[8] = fmaxf(fmaxf(red[0], red[1]), fmaxf(red[2], red[3]));
    __syncthreads();
    float M = red[8];
    if (tid < 256) {
        float e = __expf(sc[tid] - M);
        sc[tid] = e;
        float s = e;
        #pragma unroll
        for (int off = 32; off > 0; off >>= 1)
            s += __shfl_xor(s, off);
        if (lane == 0) red[w] = s;
    }
    __syncthreads();
    if (tid == 0)
        red[9] = ((red[0] + red[1]) + (red[2] + red[3]));
    __syncthreads();
    {
        float a = 0.f;
        for (int i = 0; i < 32; ++i) {
            int sp2 = w * 32 + i;
            a = fmaf(sc[sp2], epL[sp2 * 64 + lane], a);
        }
        part[w * 64 + lane] = a;
    }
    __syncthreads();
    if (tid < 64) {
        float s = 0.f;
        #pragma unroll
        for (int ww = 0; ww < 8; ++ww) s += part[ww * 64 + tid];
        coh_store(&ctxsumOut[(tid >> 2) * 256 + b * 4 + (tid & 3)], s);
    }
    if (tid == 0) {
        coh_store(&mSOut[b], M);
        coh_store(&mSOut[64 + b], red[9]);
    }
    __syncthreads();
}

// ---- combined ctx quads for a wave (lane = b) ----------------------------
__device__ __forceinline__ void load_ctx_quads(
    int t, int w, int lane,
    const float* __restrict__ ctxsumH, const float* __restrict__ mSbuf,
    float4& c0, float4& c1)
{
    const float* mS = mSbuf + (size_t)(t - 1) * 256;
    float m0 = mS[lane],       S0 = mS[64 + lane];
    float m1 = mS[128 + lane], S1 = mS[192 + lane];
    float M  = fmaxf(m0, m1);
    float e0 = __expf(m0 - M), e1 = __expf(m1 - M);
    float inv = 1.0f / (e0 * S0 + e1 * S1);
    e0 *= inv; e1 *= inv;
    const float4* a0 = (const float4*)(ctxsumH + (size_t)(t - 1) * 8192);
    const float4* a1 = (const float4*)(ctxsumH + (size_t)(t - 1) * 8192 + 4096);
    float4 x0 = a0[(w * 2 + 0) * 64 + lane];
    float4 y0 = a1[(w * 2 + 0) * 64 + lane];
    float4 x1 = a0[(w * 2 + 1) * 64 + lane];
    float4 y1 = a1[(w * 2 + 1) * 64 + lane];
    c0 = make_float4(e0 * x0.x + e1 * y0.x, e0 * x0.y + e1 * y0.y,
                     e0 * x0.z + e1 * y0.z, e0 * x0.w + e1 * y0.w);
    c1 = make_float4(e0 * x1.x + e1 * y1.x, e0 * x1.y + e1 * y1.y,
                     e0 * x1.z + e1 * y1.z, e0 * x1.w + e1 * y1.w);
}

// ---- persistent decoder: 128 attn-half blocks + 128 LSTM blocks ----------
// Dynamic LDS layout (149504 B): scratch@0 (attn 4608 / lstm part 8192 —
// DISJOINT block roles) | apL@4608 (16384) | epL@20992 (16384).
// attnFlagsR/lstmFlagsR: 8 replicas x 128 words each (R19 contention win).
extern __shared__ float dynsmem[];
__global__ __launch_bounds__(512) void k_dec_persistent(
    const float* __restrict__ encHend,
    float* __restrict__ dechH,            // [96][quad 32768]
    float* __restrict__ cT,
    const float* __restrict__ Whh,        // t=0 h-part
    const float* __restrict__ Wh,         // t>=1 fused h-part
    const float* __restrict__ Wc,         // ctx part
    const float* __restrict__ g0, const float* __restrict__ bprime,
    const float* __restrict__ Wh_pT, const float* __restrict__ bh_p,
    const float* __restrict__ WahT,  const float* __restrict__ v,
    const float* __restrict__ attnPreT, const float* __restrict__ encProj,
    float* __restrict__ ctxsumH,          // [96][2][4096]
    float* __restrict__ mSbuf,            // [96][256]
    unsigned* attnFlagsR, unsigned* lstmFlagsR)
{
    float* smem = dynsmem;                // attn scratch 4608 / lstm part 8192
    float* apL  = dynsmem + 4608;         // 16384: [h][s']   (attn only)
    float* epL  = apL + 16384;            // 16384: [s'][h2]  (attn only)
    int tid = threadIdx.x;
    int lane = tid & 63;
    int w = __builtin_amdgcn_readfirstlane(tid >> 6);
    int bi = blockIdx.x;
    int rep = bi & 7;
    const unsigned* myLstmF = lstmFlagsR + rep * 128;
    const unsigned* myAttnF = attnFlagsR + rep * 128;
    if (bi < 128) {
        int b = bi & 63, half = bi >> 6;
        {
            const float4* src = (const float4*)(attnPreT + (size_t)b * 32768 + half * 256);
            float4* dst = (float4*)apL;
            for (int i = tid; i < 4096; i += 512) {
                int h = i >> 6, qc = i & 63;
                dst[i] = src[(size_t)h * 128 + qc];
            }
        }
        {
            const float4* src = (const float4*)(encProj + ((size_t)b * 512 + half * 256) * 64);
            float4* dst = (float4*)epL;
            for (int i = tid; i < 4096; i += 512)
                dst[i] = src[i];
        }
        __syncthreads();
        for (int t = 0; t < 96; ++t) {
            if (t) wait_group(myLstmF, (w & 3) * 32, 31, (unsigned)t);
            const float* hc = t ? dechH + (size_t)(t - 1) * 32768 : encHend;
            attention_half(b, tid, w, lane, hc, Wh_pT, bh_p, WahT, v,
                           apL, epL,
                           ctxsumH + (size_t)t * 8192 + half * 4096,
                           mSbuf + (size_t)t * 256 + half * 128, smem);
            post_flag_rep(attnFlagsR, 128, bi, (unsigned)(t + 1));
        }
    } else {
        int u0A = (bi - 128) * 2;
        int u0B = u0A + 256;
        const float4* Whh4 = (const float4*)Whh;
        const float4* Wh4  = (const float4*)Wh;
        const float4* Wc4  = (const float4*)Wc;
        // c-state: wave0 threads hold pair A, wave1 threads hold pair B.
        float2 creg = make_float2(0.f, 0.f);
        if (tid < 64) {
            creg.x = cT[u0A * 64 + tid]; creg.y = cT[(u0A + 1) * 64 + tid];
        } else if (tid < 128) {
            creg.x = cT[u0B * 64 + (tid - 64)];
            creg.y = cT[(u0B + 1) * 64 + (tid - 64)];
        }
        for (int t = 0; t < 96; ++t) {
            if (t) wait_lstm_inputs(myAttnF, myLstmF, w, (unsigned)t);
            const float* hc = t ? dechH + (size_t)(t - 1) * 32768 : encHend;
            float* hn = dechH + (size_t)t * 32768;
            float accA[8], accB[8];
            #pragma unroll
            for (int r = 0; r < 8; ++r) { accA[r] = 0.f; accB[r] = 0.f; }
            if (t == 0) {
                accum_seg_pf2<16>(accA, accB, (const float4*)hc, w * 16,
                                  Whh4, 128, u0A, u0B, lane);
                lstm_finish2<true>(u0A, u0B, tid, w, accA, accB, creg,
                                   nullptr, g0, hn, smem);
            } else {
                float4 cq0, cq1;
                load_ctx_quads(t, w, lane, ctxsumH, mSbuf, cq0, cq1);
                accum_seg_pf2<16>(accA, accB, (const float4*)hc, w * 16,
                                  Wh4, 128, u0A, u0B, lane);
                accum_ctx_reg(accA, cq0, cq1, Wc4, u0A, w);
                accum_ctx_reg(accB, cq0, cq1, Wc4, u0B, w);
                lstm_finish2<false>(u0A, u0B, tid, w, accA, accB, creg,
                                    bprime, nullptr, hn, smem);
            }
            post_flag_rep(lstmFlagsR, 128, bi - 128, (unsigned)(t + 1));
        }
    }
}

// ---- post-pass: dout[b][tau] = Wo[255].[h^{(tau+1)}; ctx_tau] + bo[255] --
__global__ __launch_bounds__(256) void k_dout(
    const float* __restrict__ dechH,
    const float* __restrict__ ctxsumH, const float* __restrict__ mSbuf,
    const float* __restrict__ Wo, const float* __restrict__ bo,
    float* __restrict__ dout)
{
    __shared__ float part[256];
    int tau = blockIdx.x;            // 0..95
    int tid = threadIdx.x;
    int lane = tid & 63;             // = b
    int w = tid >> 6;                // 0..3
    const float* hq = dechH + (size_t)tau * 32768;
    const float* wrow = Wo + 255 * 576;
    float acc = 0.f;
    for (int i = w * 128; i < w * 128 + 128; ++i)
        acc = fmaf(wrow[i], hq[(i >> 2) * 256 + lane * 4 + (i & 3)], acc);
    part[w * 64 + lane] = acc;
    __syncthreads();
    if (tid < 64) {
        int b = tid;
        const float* mS = mSbuf + (size_t)tau * 256;
        float m0 = mS[b],       S0 = mS[64 + b];
        float m1 = mS[128 + b], S1 = mS[192 + b];
        float M  = fmaxf(m0, m1);
        float e0 = __expf(m0 - M), e1 = __expf(m1 - M);
        float inv = 1.0f / (e0 * S0 + e1 * S1);
        e0 *= inv; e1 *= inv;
        const float* cs0 = ctxsumH + (size_t)tau * 8192;
        const float* cs1 = cs0 + 4096;
        float a2 = bo[255];
        for (int h2 = 0; h2 < 64; ++h2) {
            int idx = (h2 >> 2) * 256 + b * 4 + (h2 & 3);
            a2 = fmaf(wrow[512 + h2], e0 * cs0[idx] + e1 * cs1[idx], a2);
        }
        float s = a2 + part[b] + part[64 + b] + part[128 + b] + part[192 + b];
        dout[b * 96 + tau] = s;
    }
}

} // namespace

extern "C" void kernel_launch(void* const* d_in, const int* in_sizes, int n_in,
                              void* d_out, int out_size, void* d_ws, size_t ws_size,
                              hipStream_t stream)
{
    (void)in_sizes; (void)n_in; (void)out_size; (void)ws_size;
    const float* input_seq = (const float*)d_in[0];
    const float* h0     = (const float*)d_in[1];
    const float* c0     = (const float*)d_in[2];
    const float* W_ih_e = (const float*)d_in[3];
    const float* W_hh_e = (const float*)d_in[4];
    const float* b_e    = (const float*)d_in[5];
    const float* W_ih_d = (const float*)d_in[6];
    const float* W_hh_d = (const float*)d_in[7];
    const float* b_d    = (const float*)d_in[8];
    const float* We_p   = (const float*)d_in[9];
    const float* be_p   = (const float*)d_in[10];
    const float* Wh_p   = (const float*)d_in[11];
    const float* bh_p   = (const float*)d_in[12];
    const float* Wa     = (const float*)d_in[13];
    const float* ba     = (const float*)d_in[14];
    const float* v      = (const float*)d_in[15];
    const float* Wo     = (const float*)d_in[16];
    const float* bo     = (const float*)d_in[17];
    float* out = (float*)d_out;

    // Flag replicas: enc 8x256 | attn 8x128 | lstm 8x128 = 4096 words (16KB).
    unsigned* encFlagsR  = (unsigned*)d_ws;     // [8][256]
    unsigned* attnFlagsR = encFlagsR + 2048;    // [8][128]
    unsigned* lstmFlagsR = attnFlagsR + 1024;   // [8][128]
    float* ws       = (float*)d_ws + 4096;      // 16KB offset
    float* xT       = ws;                       // 8388608 (dead after enc/g0)
    float* encH     = xT + 8388608;             // 513*32768 = 16809984
    float* cT       = encH + 16809984;          // 32768
    float* We_pT    = cT + 32768;               // 32768
    float* Wh_pT    = We_pT + 32768;            // 32768
    float* WahT     = Wh_pT + 32768;            // 4096
    float* WaeT     = WahT + 4096;              // 4096
    float* encProj  = WaeT + 4096;              // 2097152
    float* attnPre  = encProj + 2097152;        // 2097152
    float* dechH    = attnPre + 2097152;        // 96*32768 = 3145728
    float* ctxsumH  = dechH + 3145728;          // 96*2*4096 = 786432
    float* mSbuf    = ctxsumH + 786432;         // 96*256 = 24576
    float* Wh       = mSbuf + 24576;            // 2048*512 = 1048576
    float* Wc       = Wh + 1048576;             // 2048*64 = 131072
    float* bprime   = Wc + 131072;              // 2048
    float* g0       = bprime + 2048;            // 2048*64 = 131072
    float* attnPreT = xT;                       // aliases dead xT region (2M)

    (void)hipFuncSetAttribute((const void*)k_dec_persistent,
                              hipFuncAttributeMaxDynamicSharedMemorySize, 149504);

    (void)hipMemsetAsync(d_ws, 0, 16384, stream); // zero all flag replicas
    k_transpose_input<<<2048, 256, 0, stream>>>(input_seq, (float4*)xT);
    k_prep<<<544, 256, 0, stream>>>(We_p, Wh_p, h0, c0, Wa,
                                    We_pT, Wh_pT, encH, cT, WahT, WaeT);
    k_prep_wcomb<<<2048, 256, 0, stream>>>(W_ih_d, W_hh_d, Wo, b_d, bo,
                                           Wh, Wc, bprime);
    k_prep_g0<<<512, 256, 0, stream>>>((const float4*)(xT + (size_t)511 * 16384),
                                       W_ih_d, b_d, g0);
    k_enc_persistent<<<256, 512, 0, stream>>>((const float4*)xT, encH, cT,
                                              W_ih_e, W_hh_e, b_e, encFlagsR);
    k_proj_attn<<<1024, 256, 0, stream>>>(encH, We_pT, be_p, WaeT, ba,
                                          encProj, attnPre);
    k_attn_transpose<<<512, 256, 0, stream>>>(attnPre, attnPreT);
    k_dec_persistent<<<256, 512, 149504, stream>>>(encH + (size_t)512 * 32768,
                                                   dechH, cT,
                                                   W_hh_d, Wh, Wc, g0, bprime,
                                                   Wh_pT, bh_p, WahT, v,
                                                   attnPreT, encProj,
                                                   ctxsumH, mSbuf,
                                                   attnFlagsR, lstmFlagsR);
    k_dout<<<96, 256, 0, stream>>>(dechH, ctxsumH, mSbuf, Wo, bo, out);
}